// Round 11
// baseline (205.294 us; speedup 1.0000x reference)
//
#include <hip/hip_runtime.h>
#include <math.h>

// Problem constants: B=4, C=64, H=128, W=128, K=9, O=64

typedef short v8s __attribute__((ext_vector_type(8)));
typedef float v4f __attribute__((ext_vector_type(4)));

__device__ __forceinline__ float fast_tanh(float a) {
    float aa = fabsf(a);
    float e = __expf(2.f * aa);
    float t = 1.f - 2.f / (e + 1.f);   // e==inf -> t = 1
    return copysignf(t, a);
}

__device__ __forceinline__ float bf2f(short s) {
    union { unsigned u; float f; } v;
    v.u = ((unsigned)(unsigned short)s) << 16;
    return v.f;
}

// ---------------------------------------------------------------------------
// Pack helper: w_strip -> bf16 A-fragment order.
// w_pack[(((k*4+og)*2+kk)*64 + lane)*8 + j] = bf16( w[(o*64+c)*9+k] )
//   with o = og*16 + (lane&15), c = kk*32 + (lane>>4)*8 + j.
// ---------------------------------------------------------------------------
__device__ __forceinline__ void pack_one(
    const float* __restrict__ w_strip, short* __restrict__ w_pack, int idx)
{
    int j    = idx & 7;
    int lane = (idx >> 3) & 63;
    int kk   = (idx >> 9) & 1;
    int og   = (idx >> 10) & 3;
    int k    = idx >> 12;
    int c = (kk << 5) + ((lane >> 4) << 3) + j;
    int o = (og << 4) + (lane & 15);
    union { short s; __bf16 h; } u;
    u.h = (__bf16)w_strip[(o * 64 + c) * 9 + k];
    w_pack[idx] = u.s;
}

// Standalone pack kernel (fallback path only).
__global__ __launch_bounds__(256) void k_pack(
    const float* __restrict__ w_strip, short* __restrict__ w_pack)
{
    pack_one(w_strip, w_pack, blockIdx.x * 256 + threadIdx.x);
}

// ---------------------------------------------------------------------------
// Kernel 0: NCHW fp32 -> NHWC bf16 transpose of x, with w_pack fused into
// the first 144 blocks AND grid-stride zeroing of the atomic-accumulation
// region (off_raw/th_raw/stats/out_stats) -- replaces the memset dispatch.
// grid 1024 (b * 256 chunks of 64 px), block 256.
// ---------------------------------------------------------------------------
__global__ __launch_bounds__(256) void k_tr(
    const float* __restrict__ x, short* __restrict__ xt,
    const float* __restrict__ w_strip, short* __restrict__ w_pack,
    float4* __restrict__ zbuf)   // 295076 float4 = 1180304 floats
{
    __shared__ float l[64][65];
    const int t    = threadIdx.x;
    const int lane = t & 63;
    const int wv   = t >> 6;
    const int b    = blockIdx.x >> 8;
    const int pix0 = (blockIdx.x & 255) << 6;

    // zero the accumulation region (runs before k_conv on the stream)
    const float4 z4 = {0.f, 0.f, 0.f, 0.f};
    for (int i = blockIdx.x * 256 + t; i < 295076; i += 262144)
        zbuf[i] = z4;

#pragma unroll
    for (int it = 0; it < 16; ++it) {
        int c = (wv << 4) + it;
        l[lane][c] = x[(((size_t)(b << 6) + c) << 14) + pix0 + lane];
    }
    __syncthreads();
    {
        const int p   = t >> 2;
        const int c16 = (t & 3) << 4;
        union { v8s s8; __bf16 hh[8]; } u0, u1;
#pragma unroll
        for (int j = 0; j < 8; ++j) {
            u0.hh[j] = (__bf16)l[p][c16 + j];
            u1.hh[j] = (__bf16)l[p][c16 + 8 + j];
        }
        short* dst = xt + (((size_t)(b << 14) + pix0 + p) << 6) + c16;
        *(v8s*)dst = u0.s8;
        *(v8s*)(dst + 8) = u1.s8;
    }
    // fused w_pack (36864 elements over first 144 blocks)
    if (blockIdx.x < 144)
        pack_one(w_strip, w_pack, blockIdx.x * 256 + t);
}

// ---------------------------------------------------------------------------
// Kernel 1: fused 3x3 conv (off) + 5x5 conv (theta), channel-split 8-way.
// Tile: 32 wide x 8 tall outputs; LDS tile[12][36] (conflict-free window
// reads). Register double-buffer staging with RAW barriers (lgkmcnt only,
// no vmcnt drain). grid (4,16,32): z = b*8+split, 8 blocks/CU resident.
// ---------------------------------------------------------------------------
__global__ __launch_bounds__(256, 8) void k_conv(
    const float* __restrict__ x,
    const float* __restrict__ w_off, const float* __restrict__ b_off,
    const float* __restrict__ w_th,  const float* __restrict__ b_th,
    float* __restrict__ off_raw, float* __restrict__ th_raw)
{
    __shared__ float tile[12][36];
    const int t  = threadIdx.x;
    const int tx = t & 31, ty = t >> 5;
    const int z  = blockIdx.z;
    const int b  = z >> 3, sp = z & 7;
    const int c0 = sp << 3;
    const int h0 = blockIdx.y << 3, w0 = blockIdx.x << 5;

    // hoisted staging geometry (constant across channels)
    const int r1 = t / 36,        cc1 = t - r1 * 36;
    const int e2 = t + 256;
    const int r2 = e2 / 36,       cc2 = e2 - r2 * 36;
    const int hh1 = h0 + r1 - 2,  ww1 = w0 + cc1 - 2;
    const int hh2 = h0 + r2 - 2,  ww2 = w0 + cc2 - 2;
    const bool va1 = (hh1 >= 0 && hh1 < 128 && ww1 >= 0 && ww1 < 128);
    const bool va2 = (t < 176) && (hh2 >= 0 && hh2 < 128 && ww2 >= 0 && ww2 < 128);
    const int of1 = (hh1 << 7) + ww1;
    const int of2 = (hh2 << 7) + ww2;
    const float* xb = x + (((size_t)(b << 6) + c0) << 14);

    float accO[9], accT[9];
#pragma unroll
    for (int k = 0; k < 9; ++k) { accO[k] = 0.f; accT[k] = 0.f; }

    // prologue: issue channel 0 stage loads
    float ra = va1 ? xb[of1] : 0.f;
    float rb = va2 ? xb[of2] : 0.f;

    for (int ci = 0; ci < 8; ++ci) {
        const int c = c0 + ci;
        // barrier 1: previous compute finished reading tile (lgkm only)
        __builtin_amdgcn_sched_barrier(0);
        asm volatile("s_waitcnt lgkmcnt(0)" ::: "memory");
        __builtin_amdgcn_s_barrier();
        __builtin_amdgcn_sched_barrier(0);

        // write staged channel to LDS
        tile[r1][cc1] = ra;
        if (t < 176) tile[r2][cc2] = rb;

        // issue next channel's stage loads (fly across barrier + compute)
        if (ci < 7) {
            const float* xp = xb + ((size_t)(ci + 1) << 14);
            ra = va1 ? xp[of1] : 0.f;
            rb = va2 ? xp[of2] : 0.f;
        }

        // barrier 2: LDS writes visible (lgkm only, vmcnt NOT drained)
        __builtin_amdgcn_sched_barrier(0);
        asm volatile("s_waitcnt lgkmcnt(0)" ::: "memory");
        __builtin_amdgcn_s_barrier();
        __builtin_amdgcn_sched_barrier(0);

        float win[5][5];
#pragma unroll
        for (int i = 0; i < 5; ++i)
#pragma unroll
            for (int j = 0; j < 5; ++j)
                win[i][j] = tile[ty + i][tx + j];

#pragma unroll
        for (int k = 0; k < 9; ++k) {
            const float* wo = w_off + (size_t)((k << 6) + c) * 9;
            float a = accO[k];
#pragma unroll
            for (int i = 0; i < 3; ++i)
#pragma unroll
                for (int j = 0; j < 3; ++j)
                    a = fmaf(win[i + 1][j + 1], wo[i * 3 + j], a);
            accO[k] = a;

            const float* wt = w_th + (size_t)((k << 6) + c) * 25;
            float bb = accT[k];
#pragma unroll
            for (int i = 0; i < 5; ++i)
#pragma unroll
                for (int j = 0; j < 5; ++j)
                    bb = fmaf(win[i][j], wt[i * 5 + j], bb);
            accT[k] = bb;
        }
    }

    const int pix = ((h0 + ty) << 7) + (w0 + tx);
#pragma unroll
    for (int k = 0; k < 9; ++k) {
        float vo = accO[k] + (sp == 0 ? b_off[k] : 0.f);
        float vt = accT[k] + (sp == 0 ? b_th[k]  : 0.f);
        atomicAdd(&off_raw[((b * 9 + k) << 14) + pix], vo);
        atomicAdd(&th_raw [((b * 9 + k) << 14) + pix], vt);
    }
}

// ---------------------------------------------------------------------------
// Kernel 1b: GN stats (sum, sumsq) per (b,k) for off and theta maps.
// ---------------------------------------------------------------------------
__global__ __launch_bounds__(256) void k_stats(
    const float* __restrict__ off_raw, const float* __restrict__ th_raw,
    float* __restrict__ stats)
{
    const int id  = blockIdx.x;          // 0..71
    const int arr = id >= 36;
    const int rem = id - arr * 36;       // b*9+k
    const float4* src = (const float4*)((arr ? th_raw : off_raw) + (rem << 14));

    float s1 = 0.f, s2 = 0.f;
    for (int i = threadIdx.x; i < 4096; i += 256) {
        float4 v = src[i];
        s1 += v.x + v.y + v.z + v.w;
        s2 += v.x * v.x + v.y * v.y + v.z * v.z + v.w * v.w;
    }
#pragma unroll
    for (int d = 32; d; d >>= 1) { s1 += __shfl_down(s1, d, 64); s2 += __shfl_down(s2, d, 64); }

    __shared__ float ls1[4], ls2[4];
    const int wv = threadIdx.x >> 6;
    if ((threadIdx.x & 63) == 0) { ls1[wv] = s1; ls2[wv] = s2; }
    __syncthreads();
    if (threadIdx.x == 0) {
        stats[arr * 72 + rem]      = ls1[0] + ls1[1] + ls1[2] + ls1[3];
        stats[arr * 72 + 36 + rem] = ls2[0] + ls2[1] + ls2[2] + ls2[3];
    }
}

// ---------------------------------------------------------------------------
// Kernel 2: bf16-NHWC gather + MFMA strip contraction, DEPTH-2 pipelined.
// grid 2048 (B * 512 chunks of 32 px), block 256 (4 waves), XCD swizzle.
// NOW 8 blocks/CU resident (launch_bounds (256,8)) for TLP latency hiding.
// ---------------------------------------------------------------------------
__global__ __launch_bounds__(256, 8) void k_sample_strip3(
    const short* __restrict__ xt,
    const float* __restrict__ off_raw, const float* __restrict__ th_raw,
    const float* __restrict__ stats,
    const float* __restrict__ g_off, const float* __restrict__ be_off,
    const float* __restrict__ g_th,  const float* __restrict__ be_th,
    const short* __restrict__ w_pack, const float* __restrict__ b_strip,
    float* __restrict__ out, float* __restrict__ out_stats)
{
    __shared__ __align__(16) short smem[2][2048];
    const int t    = threadIdx.x;
    const int lane = t & 63;
    const int wv   = __builtin_amdgcn_readfirstlane(t >> 6);
    const int bid  = blockIdx.x;
    const int blk  = ((bid & 7) << 8) + (bid >> 3);   // XCD-chunked swizzle
    const int b    = blk >> 9;
    const int pix0 = (blk & 511) << 5;
    const int l32  = lane & 31;
    const int q    = lane >> 5;
    const int p_img = pix0 + l32;
    const int h    = p_img >> 7, w = p_img & 127;
    const int i15  = lane & 15, lg = lane >> 4;
    const int cg   = (wv << 4) + (q << 3);            // channel base (8 ch)
    const int cb   = (wv << 1) + q;                   // c-block in LDS

    // ---- GN constants (groups 1,2; m in 5..8) ----
    const float inv_cnt = 1.f / (3.f * 16384.f);
    float muO1, isO1, muT1, isT1, muO2, isO2, muT2, isT2;
    {
        float s, qq, mu;
        s = stats[b*9+3] + stats[b*9+4] + stats[b*9+5];
        qq = stats[36+b*9+3] + stats[36+b*9+4] + stats[36+b*9+5];
        mu = s * inv_cnt; muO1 = mu;
        isO1 = rsqrtf(fmaxf(qq * inv_cnt - mu * mu, 0.f) + 1e-5f);
        s = stats[b*9+6] + stats[b*9+7] + stats[b*9+8];
        qq = stats[36+b*9+6] + stats[36+b*9+7] + stats[36+b*9+8];
        mu = s * inv_cnt; muO2 = mu;
        isO2 = rsqrtf(fmaxf(qq * inv_cnt - mu * mu, 0.f) + 1e-5f);
        s = stats[72+b*9+3] + stats[72+b*9+4] + stats[72+b*9+5];
        qq = stats[108+b*9+3] + stats[108+b*9+4] + stats[108+b*9+5];
        mu = s * inv_cnt; muT1 = mu;
        isT1 = rsqrtf(fmaxf(qq * inv_cnt - mu * mu, 0.f) + 1e-5f);
        s = stats[72+b*9+6] + stats[72+b*9+7] + stats[72+b*9+8];
        qq = stats[108+b*9+6] + stats[108+b*9+7] + stats[108+b*9+8];
        mu = s * inv_cnt; muT2 = mu;
        isT2 = rsqrtf(fmaxf(qq * inv_cnt - mu * mu, 0.f) + 1e-5f);
    }

    // ---- per-m deformation params: z (tan), f*cos, f*sin ----
    float zt[4], cyv[4], cxv[4];
#pragma unroll
    for (int m = 5; m <= 8; ++m) {
        const int mi = m - 5;
        float tv = th_raw [((b * 9 + m) << 14) + p_img];
        float ov = off_raw[((b * 9 + m) << 14) + p_img];
        float muT = (m == 5) ? muT1 : muT2, isT = (m == 5) ? isT1 : isT2;
        float muO = (m == 5) ? muO1 : muO2, isO = (m == 5) ? isO1 : isO2;
        float z = (tv - muT) * isT * g_th[m] + be_th[m];
        float f = fast_tanh((ov - muO) * isO * g_off[m] + be_off[m]);
        float r = rsqrtf(1.f + z * z);   // cos(arctan z)
        zt[mi]  = z;
        cyv[mi] = f * r;
        cxv[mi] = z * r * f;
    }

    const short* xtb = xt + ((size_t)b << 20);

    // coords for k != 4 (k==4 handled exactly, no clamp needed)
    auto coords = [&](int k, float& cwy, float& cwx) -> int {
        const int s  = k - 4;
        const int mi = (s < 0 ? -s : s) - 1;
        const float fs = (float)s;
        float yy = (float)h + fs + fs * zt[mi] + cyv[mi];
        float xx = (float)w + 2.f * fs - cxv[mi];
        yy = fminf(fmaxf(yy, 0.f), 127.f);
        xx = fminf(fmaxf(xx, 0.f), 127.f);
        int y0 = min((int)yy, 126), x0 = min((int)xx, 126);
        cwy = yy - (float)y0; cwx = xx - (float)x0;
        return (y0 << 7) + x0;
    };

    v8s Gb[2][4];    // depth-2 gather buffers
    v8s Af[2][2];    // A-fragments, depth-2
    float wyv[2], wxv[2];

    auto issueG = [&](int k) {
        if (k == 4) {
            const short* bb = xtb + ((size_t)p_img << 6) + cg;
            Gb[k & 1][0] = *(const v8s*)bb;
        } else {
            int cidx = coords(k, wyv[k & 1], wxv[k & 1]);
            const short* bb = xtb + ((size_t)cidx << 6) + cg;
            Gb[k & 1][0] = *(const v8s*)bb;
            Gb[k & 1][1] = *(const v8s*)(bb + 64);
            Gb[k & 1][2] = *(const v8s*)(bb + 8192);
            Gb[k & 1][3] = *(const v8s*)(bb + 8256);
        }
    };
    auto issueA = [&](int k) {
        const short* wa = w_pack + (((k << 2) + wv) << 10) + (lane << 3);
        Af[k & 1][0] = *(const v8s*)wa;
        Af[k & 1][1] = *(const v8s*)(wa + 512);
    };

    // prologue: depth-2 fill
    issueG(0); issueA(0);
    issueG(1); issueA(1);

    v4f acc[2];
    acc[0] = (v4f)0.f; acc[1] = (v4f)0.f;

#pragma unroll
    for (int k = 0; k < 9; ++k) {
        // 1) combine gathers for k (counted vmcnt wait; k+1's stay in flight)
        float vj[8];
        if (k == 4) {
#pragma unroll
            for (int j = 0; j < 8; ++j) vj[j] = bf2f(Gb[k & 1][0][j]);
        } else {
            const float cwy = wyv[k & 1], cwx = wxv[k & 1];
#pragma unroll
            for (int j = 0; j < 8; ++j) {
                float c00 = bf2f(Gb[k & 1][0][j]), c01 = bf2f(Gb[k & 1][1][j]);
                float c10 = bf2f(Gb[k & 1][2][j]), c11 = bf2f(Gb[k & 1][3][j]);
                float top = fmaf(cwx, c01 - c00, c00);
                float bot = fmaf(cwx, c11 - c10, c10);
                vj[j] = fmaf(cwy, bot - top, top);
            }
        }

        // 2) issue gathers for k+2 into the just-freed buffer
        if (k < 7) issueG(k + 2);

        // 3) pack bf16 B-chunk, write LDS
        union { v8s s8; __bf16 hh[8]; } u;
#pragma unroll
        for (int j = 0; j < 8; ++j) u.hh[j] = (__bf16)vj[j];
        *(v8s*)&smem[k & 1][((cb << 5) + l32) << 3] = u.s8;

        // 4) raw barrier: wait LDS ops only, do NOT drain vmcnt
        __builtin_amdgcn_sched_barrier(0);
        asm volatile("s_waitcnt lgkmcnt(0)" ::: "memory");
        __builtin_amdgcn_s_barrier();
        __builtin_amdgcn_sched_barrier(0);

        // 5) MFMA; setprio around the MFMA cluster (T5)
        __builtin_amdgcn_s_setprio(1);
#pragma unroll
        for (int n = 0; n < 2; ++n) {
            int p16 = (n << 4) + i15;
            v8s b0 = *(const v8s*)&smem[k & 1][((lg << 5) + p16) << 3];
            v8s b1 = *(const v8s*)&smem[k & 1][(((lg + 4) << 5) + p16) << 3];
            acc[n] = __builtin_amdgcn_mfma_f32_16x16x32_bf16(Af[k & 1][0], b0, acc[n], 0, 0, 0);
            acc[n] = __builtin_amdgcn_mfma_f32_16x16x32_bf16(Af[k & 1][1], b1, acc[n], 0, 0, 0);
        }
        __builtin_amdgcn_s_setprio(0);

        // 6) issue A-frags for k+2 into the just-freed Af buffer
        if (k < 7) issueA(k + 2);
    }

    // epilogue: D col=lane&15 (pixel), row=(lane>>4)*4+reg (o) + fused GN stats
#pragma unroll
    for (int r = 0; r < 4; ++r) {
        int o = (wv << 4) + (lg << 2) + r;
        float bias = b_strip[o];
        float v0 = acc[0][r] + bias;
        float v1 = acc[1][r] + bias;
        float* op = out + (((size_t)(b << 6) + o) << 14) + pix0 + i15;
        op[0]  = v0;
        op[16] = v1;
        float s1 = v0 + v1;
        float s2 = v0 * v0 + v1 * v1;
#pragma unroll
        for (int d = 1; d <= 8; d <<= 1) {
            s1 += __shfl_xor(s1, d, 64);
            s2 += __shfl_xor(s2, d, 64);
        }
        if (i15 == 0) {
            atomicAdd(&out_stats[(b << 6) + o], s1);
            atomicAdd(&out_stats[256 + (b << 6) + o], s2);
        }
    }
}

// ---------------------------------------------------------------------------
// Kernel 2 (OLD fallback, NCHW fp32 gather): used when ws can't hold xt.
// ---------------------------------------------------------------------------
__global__ __launch_bounds__(256) void k_sample_strip_old(
    const float* __restrict__ x,
    const float* __restrict__ off_raw, const float* __restrict__ th_raw,
    const float* __restrict__ stats,
    const float* __restrict__ g_off, const float* __restrict__ be_off,
    const float* __restrict__ g_th,  const float* __restrict__ be_th,
    const short* __restrict__ w_pack, const float* __restrict__ b_strip,
    float* __restrict__ out)
{
    __shared__ __align__(16) short smem[64 * 64];
    const int t    = threadIdx.x;
    const int lane = t & 63;
    const int wv   = __builtin_amdgcn_readfirstlane(t >> 6);
    const int bid  = blockIdx.x;
    const int blk  = ((bid & 7) << 7) + (bid >> 3);
    const int b    = blk >> 8;
    const int pix0 = (blk & 255) << 6;
    const int p    = pix0 + lane;
    const int h    = p >> 7, w = p & 127;
    const int i15  = lane & 15, lg = lane >> 4;

    float muO[3], isO[3], muT[3], isT[3];
    const float inv_cnt = 1.f / (3.f * 16384.f);
#pragma unroll
    for (int g = 0; g < 3; ++g) {
        float s = 0.f, q = 0.f;
#pragma unroll
        for (int j = 0; j < 3; ++j) { s += stats[b * 9 + 3 * g + j]; q += stats[36 + b * 9 + 3 * g + j]; }
        float mu = s * inv_cnt;
        muO[g] = mu; isO[g] = rsqrtf(fmaxf(q * inv_cnt - mu * mu, 0.f) + 1e-5f);
        s = 0.f; q = 0.f;
#pragma unroll
        for (int j = 0; j < 3; ++j) { s += stats[72 + b * 9 + 3 * g + j]; q += stats[108 + b * 9 + 3 * g + j]; }
        mu = s * inv_cnt;
        muT[g] = mu; isT[g] = rsqrtf(fmaxf(q * inv_cnt - mu * mu, 0.f) + 1e-5f);
    }

    const float* xb = x + ((size_t)((b << 6) + (wv << 4)) << 14);
    v4f acc[4];
#pragma unroll
    for (int n = 0; n < 4; ++n) acc[n] = (v4f)0.f;

    for (int k = 0; k < 9; ++k) {
        float v[16];
        if (k == 4) {
#pragma unroll
            for (int ci = 0; ci < 16; ++ci) v[ci] = xb[(ci << 14) + p];
        } else {
            const int s = k - 4;
            const int m = 4 + (s < 0 ? -s : s);
            const int g = m / 3;
            float z = (th_raw[((b * 9 + m) << 14) + p] - muT[g]) * isT[g] * g_th[m] + be_th[m];
            float f = fast_tanh((off_raw[((b * 9 + m) << 14) + p] - muO[g]) * isO[g] * g_off[m] + be_off[m]);
            float r = rsqrtf(1.f + z * z);
            float fs = (float)s;
            float yy = (float)h + fs + fs * z + f * r;
            float xx = (float)w + fs + fs - z * r * f;
            yy = fminf(fmaxf(yy, 0.f), 127.f);
            xx = fminf(fmaxf(xx, 0.f), 127.f);
            int y0 = min((int)yy, 126);
            int x0 = min((int)xx, 126);
            float wy = yy - (float)y0;
            float wx = xx - (float)x0;
            const float* base = xb + (y0 << 7) + x0;
#pragma unroll
            for (int ci = 0; ci < 16; ++ci) {
                const float* qp = base + (ci << 14);
                float2 r0 = *(const float2*)qp;
                float2 r1 = *(const float2*)(qp + 128);
                float lo = fmaf(wx, r0.y - r0.x, r0.x);
                float hi = fmaf(wx, r1.y - r1.x, r1.x);
                v[ci] = fmaf(wy, hi - lo, lo);
            }
        }

        union { v8s s8; __bf16 hh[8]; } u0, u1;
#pragma unroll
        for (int ci = 0; ci < 8; ++ci) { u0.hh[ci] = (__bf16)v[ci]; u1.hh[ci] = (__bf16)v[ci + 8]; }
        *(v8s*)&smem[(lane << 6) + ((((wv << 1) + 0) + lane) & 7) * 8] = u0.s8;
        *(v8s*)&smem[(lane << 6) + ((((wv << 1) + 1) + lane) & 7) * 8] = u1.s8;
        __syncthreads();

        const short* wpk = w_pack + (((k << 2) + wv) << 10) + (lane << 3);
        v8s a0 = *(const v8s*)wpk;
        v8s a1 = *(const v8s*)(wpk + 512);

#pragma unroll
        for (int n = 0; n < 4; ++n) {
            int r = (n << 4) + i15;
            v8s b0 = *(const v8s*)&smem[(r << 6) + (((lg    ) + r) & 7) * 8];
            v8s b1 = *(const v8s*)&smem[(r << 6) + (((lg + 4) + r) & 7) * 8];
            acc[n] = __builtin_amdgcn_mfma_f32_16x16x32_bf16(a0, b0, acc[n], 0, 0, 0);
            acc[n] = __builtin_amdgcn_mfma_f32_16x16x32_bf16(a1, b1, acc[n], 0, 0, 0);
        }
        __syncthreads();
    }

#pragma unroll
    for (int r = 0; r < 4; ++r) {
        int o = (wv << 4) + (lg << 2) + r;
        float bias = b_strip[o];
        float* op = out + ((size_t)((b << 6) + o) << 14) + pix0 + i15;
#pragma unroll
        for (int n = 0; n < 4; ++n)
            op[n << 4] = acc[n][r] + bias;
    }
}

// ---------------------------------------------------------------------------
// Kernel 2b: output GN stats per (b,o). grid 256. (fallback path only)
// ---------------------------------------------------------------------------
__global__ __launch_bounds__(256) void k_stats_out(
    const float* __restrict__ out, float* __restrict__ out_stats)
{
    const int bo = blockIdx.x;
    const float4* src = (const float4*)(out + ((size_t)bo << 14));
    float s1 = 0.f, s2 = 0.f;
    for (int i = threadIdx.x; i < 4096; i += 256) {
        float4 v = src[i];
        s1 += v.x + v.y + v.z + v.w;
        s2 += v.x * v.x + v.y * v.y + v.z * v.z + v.w * v.w;
    }
#pragma unroll
    for (int d = 32; d; d >>= 1) { s1 += __shfl_down(s1, d, 64); s2 += __shfl_down(s2, d, 64); }

    __shared__ float ls1[4], ls2[4];
    const int wv = threadIdx.x >> 6;
    if ((threadIdx.x & 63) == 0) { ls1[wv] = s1; ls2[wv] = s2; }
    __syncthreads();
    if (threadIdx.x == 0) {
        out_stats[bo]       = ls1[0] + ls1[1] + ls1[2] + ls1[3];
        out_stats[256 + bo] = ls2[0] + ls2[1] + ls2[2] + ls2[3];
    }
}

// ---------------------------------------------------------------------------
// Kernel 3: output GroupNorm (16 groups of 4 channels) + ReLU, in place.
// ---------------------------------------------------------------------------
__global__ __launch_bounds__(256) void k_gn_out(
    float* __restrict__ out, const float* __restrict__ out_stats,
    const float* __restrict__ gg, const float* __restrict__ gb)
{
    const float inv_cnt = 1.f / (4.f * 16384.f);
    const int n4 = 1 << 20;
    for (int idx = blockIdx.x * 256 + threadIdx.x; idx < n4; idx += gridDim.x * 256) {
        int flat = idx << 2;
        int ch = (flat >> 14) & 63;
        int b  = flat >> 20;
        int cb = (b << 6) + ((ch >> 2) << 2);
        float s = out_stats[cb] + out_stats[cb + 1] + out_stats[cb + 2] + out_stats[cb + 3];
        float q = out_stats[256 + cb] + out_stats[256 + cb + 1] + out_stats[256 + cb + 2] + out_stats[256 + cb + 3];
        float mu   = s * inv_cnt;
        float istd = rsqrtf(fmaxf(q * inv_cnt - mu * mu, 0.f) + 1e-5f);
        float ga = gg[ch] * istd;
        float be = gb[ch] - mu * ga;
        float4 v = *reinterpret_cast<float4*>(out + flat);
        v.x = fmaxf(fmaf(v.x, ga, be), 0.f);
        v.y = fmaxf(fmaf(v.y, ga, be), 0.f);
        v.z = fmaxf(fmaf(v.z, ga, be), 0.f);
        v.w = fmaxf(fmaf(v.w, ga, be), 0.f);
        *reinterpret_cast<float4*>(out + flat) = v;
    }
}

// ---------------------------------------------------------------------------
extern "C" void kernel_launch(void* const* d_in, const int* in_sizes, int n_in,
                              void* d_out, int out_size, void* d_ws, size_t ws_size,
                              hipStream_t stream)
{
    const float* x       = (const float*)d_in[0];
    const float* w_off   = (const float*)d_in[1];
    const float* b_off   = (const float*)d_in[2];
    const float* w_th    = (const float*)d_in[3];
    const float* b_th    = (const float*)d_in[4];
    const float* g_off   = (const float*)d_in[5];
    const float* be_off  = (const float*)d_in[6];
    const float* g_th    = (const float*)d_in[7];
    const float* be_th   = (const float*)d_in[8];
    const float* w_strip = (const float*)d_in[9];
    const float* b_strip = (const float*)d_in[10];
    const float* gg      = (const float*)d_in[11];
    const float* gb      = (const float*)d_in[12];

    float* out       = (float*)d_out;
    float* ws        = (float*)d_ws;
    float* off_raw   = ws;                      // 589824 floats
    float* th_raw    = ws + 589824;             // 589824 floats
    float* stats     = ws + 1179648;            // 144 floats
    float* out_stats = ws + 1179792;            // 512 floats
    short* w_pack    = (short*)(ws + 1180304);  // 36864 shorts = 18432 floats
    short* xt        = (short*)(ws + 1198736);  // 4194304 shorts = 2097152 floats

    const size_t need_full = (size_t)(1198736 + 2097152) * sizeof(float);
    const bool big = ws_size >= need_full;

    if (big) {
        // k_tr zeroes the accumulation region + transposes + packs weights
        k_tr<<<1024, 256, 0, stream>>>(x, xt, w_strip, w_pack, (float4*)ws);
    } else {
        hipMemsetAsync(ws, 0, (size_t)1180304 * sizeof(float), stream);
        k_pack<<<144, 256, 0, stream>>>(w_strip, w_pack);
    }
    dim3 g1(4, 16, 32);
    k_conv<<<g1, 256, 0, stream>>>(x, w_off, b_off, w_th, b_th, off_raw, th_raw);
    k_stats<<<72, 256, 0, stream>>>(off_raw, th_raw, stats);
    if (big) {
        k_sample_strip3<<<2048, 256, 0, stream>>>(xt, off_raw, th_raw, stats,
                                                  g_off, be_off, g_th, be_th,
                                                  w_pack, b_strip, out, out_stats);
    } else {
        k_sample_strip_old<<<1024, 256, 0, stream>>>(x, off_raw, th_raw, stats,
                                                     g_off, be_off, g_th, be_th,
                                                     w_pack, b_strip, out);
        k_stats_out<<<256, 256, 0, stream>>>(out, out_stats);
    }
    k_gn_out<<<4096, 256, 0, stream>>>(out, out_stats, gg, gb);
}

// Round 12
// 183.749 us; speedup vs baseline: 1.1173x; 1.1173x over previous
//
#include <hip/hip_runtime.h>
#include <math.h>

// Problem constants: B=4, C=64, H=128, W=128, K=9, O=64

typedef short v8s __attribute__((ext_vector_type(8)));
typedef float v4f __attribute__((ext_vector_type(4)));

__device__ __forceinline__ float fast_tanh(float a) {
    float aa = fabsf(a);
    float e = __expf(2.f * aa);
    float t = 1.f - 2.f / (e + 1.f);   // e==inf -> t = 1
    return copysignf(t, a);
}

__device__ __forceinline__ float bf2f(short s) {
    union { unsigned u; float f; } v;
    v.u = ((unsigned)(unsigned short)s) << 16;
    return v.f;
}

// ---------------------------------------------------------------------------
// Pack helper: w_strip -> bf16 A-fragment order.
// w_pack[(((k*4+og)*2+kk)*64 + lane)*8 + j] = bf16( w[(o*64+c)*9+k] )
//   with o = og*16 + (lane&15), c = kk*32 + (lane>>4)*8 + j.
// ---------------------------------------------------------------------------
__device__ __forceinline__ void pack_one(
    const float* __restrict__ w_strip, short* __restrict__ w_pack, int idx)
{
    int j    = idx & 7;
    int lane = (idx >> 3) & 63;
    int kk   = (idx >> 9) & 1;
    int og   = (idx >> 10) & 3;
    int k    = idx >> 12;
    int c = (kk << 5) + ((lane >> 4) << 3) + j;
    int o = (og << 4) + (lane & 15);
    union { short s; __bf16 h; } u;
    u.h = (__bf16)w_strip[(o * 64 + c) * 9 + k];
    w_pack[idx] = u.s;
}

// Standalone pack kernel (fallback path only).
__global__ __launch_bounds__(256) void k_pack(
    const float* __restrict__ w_strip, short* __restrict__ w_pack)
{
    pack_one(w_strip, w_pack, blockIdx.x * 256 + threadIdx.x);
}

// ---------------------------------------------------------------------------
// Kernel 0: NCHW fp32 -> NHWC bf16 transpose of x, with w_pack fused into
// the first 144 blocks AND grid-stride zeroing of the atomic-accumulation
// region (off_raw/th_raw/stats/out_stats) -- replaces the memset dispatch.
// grid 1024 (b * 256 chunks of 64 px), block 256.
// ---------------------------------------------------------------------------
__global__ __launch_bounds__(256) void k_tr(
    const float* __restrict__ x, short* __restrict__ xt,
    const float* __restrict__ w_strip, short* __restrict__ w_pack,
    float4* __restrict__ zbuf)   // 295076 float4 = 1180304 floats
{
    __shared__ float l[64][65];
    const int t    = threadIdx.x;
    const int lane = t & 63;
    const int wv   = t >> 6;
    const int b    = blockIdx.x >> 8;
    const int pix0 = (blockIdx.x & 255) << 6;

    // zero the accumulation region (runs before k_conv on the stream)
    const float4 z4 = {0.f, 0.f, 0.f, 0.f};
    for (int i = blockIdx.x * 256 + t; i < 295076; i += 262144)
        zbuf[i] = z4;

#pragma unroll
    for (int it = 0; it < 16; ++it) {
        int c = (wv << 4) + it;
        l[lane][c] = x[(((size_t)(b << 6) + c) << 14) + pix0 + lane];
    }
    __syncthreads();
    {
        const int p   = t >> 2;
        const int c16 = (t & 3) << 4;
        union { v8s s8; __bf16 hh[8]; } u0, u1;
#pragma unroll
        for (int j = 0; j < 8; ++j) {
            u0.hh[j] = (__bf16)l[p][c16 + j];
            u1.hh[j] = (__bf16)l[p][c16 + 8 + j];
        }
        short* dst = xt + (((size_t)(b << 14) + pix0 + p) << 6) + c16;
        *(v8s*)dst = u0.s8;
        *(v8s*)(dst + 8) = u1.s8;
    }
    // fused w_pack (36864 elements over first 144 blocks)
    if (blockIdx.x < 144)
        pack_one(w_strip, w_pack, blockIdx.x * 256 + t);
}

// ---------------------------------------------------------------------------
// Kernel 1: fused 3x3 conv (off) + 5x5 conv (theta), channel-split 8-way.
// Tile: 32 wide x 8 tall outputs; LDS tile[12][36] (conflict-free window
// reads). Register double-buffer staging with RAW barriers (lgkmcnt only,
// no vmcnt drain). grid (4,16,32): z = b*8+split, 8 blocks/CU resident.
// ---------------------------------------------------------------------------
__global__ __launch_bounds__(256, 8) void k_conv(
    const float* __restrict__ x,
    const float* __restrict__ w_off, const float* __restrict__ b_off,
    const float* __restrict__ w_th,  const float* __restrict__ b_th,
    float* __restrict__ off_raw, float* __restrict__ th_raw)
{
    __shared__ float tile[12][36];
    const int t  = threadIdx.x;
    const int tx = t & 31, ty = t >> 5;
    const int z  = blockIdx.z;
    const int b  = z >> 3, sp = z & 7;
    const int c0 = sp << 3;
    const int h0 = blockIdx.y << 3, w0 = blockIdx.x << 5;

    // hoisted staging geometry (constant across channels)
    const int r1 = t / 36,        cc1 = t - r1 * 36;
    const int e2 = t + 256;
    const int r2 = e2 / 36,       cc2 = e2 - r2 * 36;
    const int hh1 = h0 + r1 - 2,  ww1 = w0 + cc1 - 2;
    const int hh2 = h0 + r2 - 2,  ww2 = w0 + cc2 - 2;
    const bool va1 = (hh1 >= 0 && hh1 < 128 && ww1 >= 0 && ww1 < 128);
    const bool va2 = (t < 176) && (hh2 >= 0 && hh2 < 128 && ww2 >= 0 && ww2 < 128);
    const int of1 = (hh1 << 7) + ww1;
    const int of2 = (hh2 << 7) + ww2;
    const float* xb = x + (((size_t)(b << 6) + c0) << 14);

    float accO[9], accT[9];
#pragma unroll
    for (int k = 0; k < 9; ++k) { accO[k] = 0.f; accT[k] = 0.f; }

    // prologue: issue channel 0 stage loads
    float ra = va1 ? xb[of1] : 0.f;
    float rb = va2 ? xb[of2] : 0.f;

    for (int ci = 0; ci < 8; ++ci) {
        const int c = c0 + ci;
        // barrier 1: previous compute finished reading tile (lgkm only)
        __builtin_amdgcn_sched_barrier(0);
        asm volatile("s_waitcnt lgkmcnt(0)" ::: "memory");
        __builtin_amdgcn_s_barrier();
        __builtin_amdgcn_sched_barrier(0);

        // write staged channel to LDS
        tile[r1][cc1] = ra;
        if (t < 176) tile[r2][cc2] = rb;

        // issue next channel's stage loads (fly across barrier + compute)
        if (ci < 7) {
            const float* xp = xb + ((size_t)(ci + 1) << 14);
            ra = va1 ? xp[of1] : 0.f;
            rb = va2 ? xp[of2] : 0.f;
        }

        // barrier 2: LDS writes visible (lgkm only, vmcnt NOT drained)
        __builtin_amdgcn_sched_barrier(0);
        asm volatile("s_waitcnt lgkmcnt(0)" ::: "memory");
        __builtin_amdgcn_s_barrier();
        __builtin_amdgcn_sched_barrier(0);

        float win[5][5];
#pragma unroll
        for (int i = 0; i < 5; ++i)
#pragma unroll
            for (int j = 0; j < 5; ++j)
                win[i][j] = tile[ty + i][tx + j];

#pragma unroll
        for (int k = 0; k < 9; ++k) {
            const float* wo = w_off + (size_t)((k << 6) + c) * 9;
            float a = accO[k];
#pragma unroll
            for (int i = 0; i < 3; ++i)
#pragma unroll
                for (int j = 0; j < 3; ++j)
                    a = fmaf(win[i + 1][j + 1], wo[i * 3 + j], a);
            accO[k] = a;

            const float* wt = w_th + (size_t)((k << 6) + c) * 25;
            float bb = accT[k];
#pragma unroll
            for (int i = 0; i < 5; ++i)
#pragma unroll
                for (int j = 0; j < 5; ++j)
                    bb = fmaf(win[i][j], wt[i * 5 + j], bb);
            accT[k] = bb;
        }
    }

    const int pix = ((h0 + ty) << 7) + (w0 + tx);
#pragma unroll
    for (int k = 0; k < 9; ++k) {
        float vo = accO[k] + (sp == 0 ? b_off[k] : 0.f);
        float vt = accT[k] + (sp == 0 ? b_th[k]  : 0.f);
        atomicAdd(&off_raw[((b * 9 + k) << 14) + pix], vo);
        atomicAdd(&th_raw [((b * 9 + k) << 14) + pix], vt);
    }
}

// ---------------------------------------------------------------------------
// Kernel 1b: GN stats (sum, sumsq) per (b,k) for off and theta maps.
// ---------------------------------------------------------------------------
__global__ __launch_bounds__(256) void k_stats(
    const float* __restrict__ off_raw, const float* __restrict__ th_raw,
    float* __restrict__ stats)
{
    const int id  = blockIdx.x;          // 0..71
    const int arr = id >= 36;
    const int rem = id - arr * 36;       // b*9+k
    const float4* src = (const float4*)((arr ? th_raw : off_raw) + (rem << 14));

    float s1 = 0.f, s2 = 0.f;
    for (int i = threadIdx.x; i < 4096; i += 256) {
        float4 v = src[i];
        s1 += v.x + v.y + v.z + v.w;
        s2 += v.x * v.x + v.y * v.y + v.z * v.z + v.w * v.w;
    }
#pragma unroll
    for (int d = 32; d; d >>= 1) { s1 += __shfl_down(s1, d, 64); s2 += __shfl_down(s2, d, 64); }

    __shared__ float ls1[4], ls2[4];
    const int wv = threadIdx.x >> 6;
    if ((threadIdx.x & 63) == 0) { ls1[wv] = s1; ls2[wv] = s2; }
    __syncthreads();
    if (threadIdx.x == 0) {
        stats[arr * 72 + rem]      = ls1[0] + ls1[1] + ls1[2] + ls1[3];
        stats[arr * 72 + 36 + rem] = ls2[0] + ls2[1] + ls2[2] + ls2[3];
    }
}

// ---------------------------------------------------------------------------
// Kernel 2: bf16-NHWC gather + MFMA strip contraction, DEPTH-2 pipelined.
// grid 2048 (B * 512 chunks of 32 px), block 256 (4 waves), XCD swizzle.
// launch_bounds (256,6): 6 blocks/CU resident, VGPR cap ~84 (no spill --
// the (256,8) attempt capped at 64 and spilled the pipeline to scratch).
// ---------------------------------------------------------------------------
__global__ __launch_bounds__(256, 6) void k_sample_strip3(
    const short* __restrict__ xt,
    const float* __restrict__ off_raw, const float* __restrict__ th_raw,
    const float* __restrict__ stats,
    const float* __restrict__ g_off, const float* __restrict__ be_off,
    const float* __restrict__ g_th,  const float* __restrict__ be_th,
    const short* __restrict__ w_pack, const float* __restrict__ b_strip,
    float* __restrict__ out, float* __restrict__ out_stats)
{
    __shared__ __align__(16) short smem[2][2048];
    const int t    = threadIdx.x;
    const int lane = t & 63;
    const int wv   = __builtin_amdgcn_readfirstlane(t >> 6);
    const int bid  = blockIdx.x;
    const int blk  = ((bid & 7) << 8) + (bid >> 3);   // XCD-chunked swizzle
    const int b    = blk >> 9;
    const int pix0 = (blk & 511) << 5;
    const int l32  = lane & 31;
    const int q    = lane >> 5;
    const int p_img = pix0 + l32;
    const int h    = p_img >> 7, w = p_img & 127;
    const int i15  = lane & 15, lg = lane >> 4;
    const int cg   = (wv << 4) + (q << 3);            // channel base (8 ch)
    const int cb   = (wv << 1) + q;                   // c-block in LDS

    // ---- GN constants (groups 1,2; m in 5..8) ----
    const float inv_cnt = 1.f / (3.f * 16384.f);
    float muO1, isO1, muT1, isT1, muO2, isO2, muT2, isT2;
    {
        float s, qq, mu;
        s = stats[b*9+3] + stats[b*9+4] + stats[b*9+5];
        qq = stats[36+b*9+3] + stats[36+b*9+4] + stats[36+b*9+5];
        mu = s * inv_cnt; muO1 = mu;
        isO1 = rsqrtf(fmaxf(qq * inv_cnt - mu * mu, 0.f) + 1e-5f);
        s = stats[b*9+6] + stats[b*9+7] + stats[b*9+8];
        qq = stats[36+b*9+6] + stats[36+b*9+7] + stats[36+b*9+8];
        mu = s * inv_cnt; muO2 = mu;
        isO2 = rsqrtf(fmaxf(qq * inv_cnt - mu * mu, 0.f) + 1e-5f);
        s = stats[72+b*9+3] + stats[72+b*9+4] + stats[72+b*9+5];
        qq = stats[108+b*9+3] + stats[108+b*9+4] + stats[108+b*9+5];
        mu = s * inv_cnt; muT1 = mu;
        isT1 = rsqrtf(fmaxf(qq * inv_cnt - mu * mu, 0.f) + 1e-5f);
        s = stats[72+b*9+6] + stats[72+b*9+7] + stats[72+b*9+8];
        qq = stats[108+b*9+6] + stats[108+b*9+7] + stats[108+b*9+8];
        mu = s * inv_cnt; muT2 = mu;
        isT2 = rsqrtf(fmaxf(qq * inv_cnt - mu * mu, 0.f) + 1e-5f);
    }

    // ---- per-m deformation params: z (tan), f*cos, f*sin ----
    float zt[4], cyv[4], cxv[4];
#pragma unroll
    for (int m = 5; m <= 8; ++m) {
        const int mi = m - 5;
        float tv = th_raw [((b * 9 + m) << 14) + p_img];
        float ov = off_raw[((b * 9 + m) << 14) + p_img];
        float muT = (m == 5) ? muT1 : muT2, isT = (m == 5) ? isT1 : isT2;
        float muO = (m == 5) ? muO1 : muO2, isO = (m == 5) ? isO1 : isO2;
        float z = (tv - muT) * isT * g_th[m] + be_th[m];
        float f = fast_tanh((ov - muO) * isO * g_off[m] + be_off[m]);
        float r = rsqrtf(1.f + z * z);   // cos(arctan z)
        zt[mi]  = z;
        cyv[mi] = f * r;
        cxv[mi] = z * r * f;
    }

    const short* xtb = xt + ((size_t)b << 20);

    // coords for k != 4 (k==4 handled exactly, no clamp needed)
    auto coords = [&](int k, float& cwy, float& cwx) -> int {
        const int s  = k - 4;
        const int mi = (s < 0 ? -s : s) - 1;
        const float fs = (float)s;
        float yy = (float)h + fs + fs * zt[mi] + cyv[mi];
        float xx = (float)w + 2.f * fs - cxv[mi];
        yy = fminf(fmaxf(yy, 0.f), 127.f);
        xx = fminf(fmaxf(xx, 0.f), 127.f);
        int y0 = min((int)yy, 126), x0 = min((int)xx, 126);
        cwy = yy - (float)y0; cwx = xx - (float)x0;
        return (y0 << 7) + x0;
    };

    v8s Gb[2][4];    // depth-2 gather buffers
    v8s Af[2][2];    // A-fragments, depth-2
    float wyv[2], wxv[2];

    auto issueG = [&](int k) {
        if (k == 4) {
            const short* bb = xtb + ((size_t)p_img << 6) + cg;
            Gb[k & 1][0] = *(const v8s*)bb;
        } else {
            int cidx = coords(k, wyv[k & 1], wxv[k & 1]);
            const short* bb = xtb + ((size_t)cidx << 6) + cg;
            Gb[k & 1][0] = *(const v8s*)bb;
            Gb[k & 1][1] = *(const v8s*)(bb + 64);
            Gb[k & 1][2] = *(const v8s*)(bb + 8192);
            Gb[k & 1][3] = *(const v8s*)(bb + 8256);
        }
    };
    auto issueA = [&](int k) {
        const short* wa = w_pack + (((k << 2) + wv) << 10) + (lane << 3);
        Af[k & 1][0] = *(const v8s*)wa;
        Af[k & 1][1] = *(const v8s*)(wa + 512);
    };

    // prologue: depth-2 fill
    issueG(0); issueA(0);
    issueG(1); issueA(1);

    v4f acc[2];
    acc[0] = (v4f)0.f; acc[1] = (v4f)0.f;

#pragma unroll
    for (int k = 0; k < 9; ++k) {
        // 1) combine gathers for k (counted vmcnt wait; k+1's stay in flight)
        float vj[8];
        if (k == 4) {
#pragma unroll
            for (int j = 0; j < 8; ++j) vj[j] = bf2f(Gb[k & 1][0][j]);
        } else {
            const float cwy = wyv[k & 1], cwx = wxv[k & 1];
#pragma unroll
            for (int j = 0; j < 8; ++j) {
                float c00 = bf2f(Gb[k & 1][0][j]), c01 = bf2f(Gb[k & 1][1][j]);
                float c10 = bf2f(Gb[k & 1][2][j]), c11 = bf2f(Gb[k & 1][3][j]);
                float top = fmaf(cwx, c01 - c00, c00);
                float bot = fmaf(cwx, c11 - c10, c10);
                vj[j] = fmaf(cwy, bot - top, top);
            }
        }

        // 2) issue gathers for k+2 into the just-freed buffer
        if (k < 7) issueG(k + 2);

        // 3) pack bf16 B-chunk, write LDS
        union { v8s s8; __bf16 hh[8]; } u;
#pragma unroll
        for (int j = 0; j < 8; ++j) u.hh[j] = (__bf16)vj[j];
        *(v8s*)&smem[k & 1][((cb << 5) + l32) << 3] = u.s8;

        // 4) raw barrier: wait LDS ops only, do NOT drain vmcnt
        __builtin_amdgcn_sched_barrier(0);
        asm volatile("s_waitcnt lgkmcnt(0)" ::: "memory");
        __builtin_amdgcn_s_barrier();
        __builtin_amdgcn_sched_barrier(0);

        // 5) MFMA; setprio around the MFMA cluster (T5)
        __builtin_amdgcn_s_setprio(1);
#pragma unroll
        for (int n = 0; n < 2; ++n) {
            int p16 = (n << 4) + i15;
            v8s b0 = *(const v8s*)&smem[k & 1][((lg << 5) + p16) << 3];
            v8s b1 = *(const v8s*)&smem[k & 1][(((lg + 4) << 5) + p16) << 3];
            acc[n] = __builtin_amdgcn_mfma_f32_16x16x32_bf16(Af[k & 1][0], b0, acc[n], 0, 0, 0);
            acc[n] = __builtin_amdgcn_mfma_f32_16x16x32_bf16(Af[k & 1][1], b1, acc[n], 0, 0, 0);
        }
        __builtin_amdgcn_s_setprio(0);

        // 6) issue A-frags for k+2 into the just-freed Af buffer
        if (k < 7) issueA(k + 2);
    }

    // epilogue: D col=lane&15 (pixel), row=(lane>>4)*4+reg (o) + fused GN stats
#pragma unroll
    for (int r = 0; r < 4; ++r) {
        int o = (wv << 4) + (lg << 2) + r;
        float bias = b_strip[o];
        float v0 = acc[0][r] + bias;
        float v1 = acc[1][r] + bias;
        float* op = out + (((size_t)(b << 6) + o) << 14) + pix0 + i15;
        op[0]  = v0;
        op[16] = v1;
        float s1 = v0 + v1;
        float s2 = v0 * v0 + v1 * v1;
#pragma unroll
        for (int d = 1; d <= 8; d <<= 1) {
            s1 += __shfl_xor(s1, d, 64);
            s2 += __shfl_xor(s2, d, 64);
        }
        if (i15 == 0) {
            atomicAdd(&out_stats[(b << 6) + o], s1);
            atomicAdd(&out_stats[256 + (b << 6) + o], s2);
        }
    }
}

// ---------------------------------------------------------------------------
// Kernel 2 (OLD fallback, NCHW fp32 gather): used when ws can't hold xt.
// ---------------------------------------------------------------------------
__global__ __launch_bounds__(256) void k_sample_strip_old(
    const float* __restrict__ x,
    const float* __restrict__ off_raw, const float* __restrict__ th_raw,
    const float* __restrict__ stats,
    const float* __restrict__ g_off, const float* __restrict__ be_off,
    const float* __restrict__ g_th,  const float* __restrict__ be_th,
    const short* __restrict__ w_pack, const float* __restrict__ b_strip,
    float* __restrict__ out)
{
    __shared__ __align__(16) short smem[64 * 64];
    const int t    = threadIdx.x;
    const int lane = t & 63;
    const int wv   = __builtin_amdgcn_readfirstlane(t >> 6);
    const int bid  = blockIdx.x;
    const int blk  = ((bid & 7) << 7) + (bid >> 3);
    const int b    = blk >> 8;
    const int pix0 = (blk & 255) << 6;
    const int p    = pix0 + lane;
    const int h    = p >> 7, w = p & 127;
    const int i15  = lane & 15, lg = lane >> 4;

    float muO[3], isO[3], muT[3], isT[3];
    const float inv_cnt = 1.f / (3.f * 16384.f);
#pragma unroll
    for (int g = 0; g < 3; ++g) {
        float s = 0.f, q = 0.f;
#pragma unroll
        for (int j = 0; j < 3; ++j) { s += stats[b * 9 + 3 * g + j]; q += stats[36 + b * 9 + 3 * g + j]; }
        float mu = s * inv_cnt;
        muO[g] = mu; isO[g] = rsqrtf(fmaxf(q * inv_cnt - mu * mu, 0.f) + 1e-5f);
        s = 0.f; q = 0.f;
#pragma unroll
        for (int j = 0; j < 3; ++j) { s += stats[72 + b * 9 + 3 * g + j]; q += stats[108 + b * 9 + 3 * g + j]; }
        mu = s * inv_cnt;
        muT[g] = mu; isT[g] = rsqrtf(fmaxf(q * inv_cnt - mu * mu, 0.f) + 1e-5f);
    }

    const float* xb = x + ((size_t)((b << 6) + (wv << 4)) << 14);
    v4f acc[4];
#pragma unroll
    for (int n = 0; n < 4; ++n) acc[n] = (v4f)0.f;

    for (int k = 0; k < 9; ++k) {
        float v[16];
        if (k == 4) {
#pragma unroll
            for (int ci = 0; ci < 16; ++ci) v[ci] = xb[(ci << 14) + p];
        } else {
            const int s = k - 4;
            const int m = 4 + (s < 0 ? -s : s);
            const int g = m / 3;
            float z = (th_raw[((b * 9 + m) << 14) + p] - muT[g]) * isT[g] * g_th[m] + be_th[m];
            float f = fast_tanh((off_raw[((b * 9 + m) << 14) + p] - muO[g]) * isO[g] * g_off[m] + be_off[m]);
            float r = rsqrtf(1.f + z * z);
            float fs = (float)s;
            float yy = (float)h + fs + fs * z + f * r;
            float xx = (float)w + fs + fs - z * r * f;
            yy = fminf(fmaxf(yy, 0.f), 127.f);
            xx = fminf(fmaxf(xx, 0.f), 127.f);
            int y0 = min((int)yy, 126);
            int x0 = min((int)xx, 126);
            float wy = yy - (float)y0;
            float wx = xx - (float)x0;
            const float* base = xb + (y0 << 7) + x0;
#pragma unroll
            for (int ci = 0; ci < 16; ++ci) {
                const float* qp = base + (ci << 14);
                float2 r0 = *(const float2*)qp;
                float2 r1 = *(const float2*)(qp + 128);
                float lo = fmaf(wx, r0.y - r0.x, r0.x);
                float hi = fmaf(wx, r1.y - r1.x, r1.x);
                v[ci] = fmaf(wy, hi - lo, lo);
            }
        }

        union { v8s s8; __bf16 hh[8]; } u0, u1;
#pragma unroll
        for (int ci = 0; ci < 8; ++ci) { u0.hh[ci] = (__bf16)v[ci]; u1.hh[ci] = (__bf16)v[ci + 8]; }
        *(v8s*)&smem[(lane << 6) + ((((wv << 1) + 0) + lane) & 7) * 8] = u0.s8;
        *(v8s*)&smem[(lane << 6) + ((((wv << 1) + 1) + lane) & 7) * 8] = u1.s8;
        __syncthreads();

        const short* wpk = w_pack + (((k << 2) + wv) << 10) + (lane << 3);
        v8s a0 = *(const v8s*)wpk;
        v8s a1 = *(const v8s*)(wpk + 512);

#pragma unroll
        for (int n = 0; n < 4; ++n) {
            int r = (n << 4) + i15;
            v8s b0 = *(const v8s*)&smem[(r << 6) + (((lg    ) + r) & 7) * 8];
            v8s b1 = *(const v8s*)&smem[(r << 6) + (((lg + 4) + r) & 7) * 8];
            acc[n] = __builtin_amdgcn_mfma_f32_16x16x32_bf16(a0, b0, acc[n], 0, 0, 0);
            acc[n] = __builtin_amdgcn_mfma_f32_16x16x32_bf16(a1, b1, acc[n], 0, 0, 0);
        }
        __syncthreads();
    }

#pragma unroll
    for (int r = 0; r < 4; ++r) {
        int o = (wv << 4) + (lg << 2) + r;
        float bias = b_strip[o];
        float* op = out + ((size_t)((b << 6) + o) << 14) + pix0 + i15;
#pragma unroll
        for (int n = 0; n < 4; ++n)
            op[n << 4] = acc[n][r] + bias;
    }
}

// ---------------------------------------------------------------------------
// Kernel 2b: output GN stats per (b,o). grid 256. (fallback path only)
// ---------------------------------------------------------------------------
__global__ __launch_bounds__(256) void k_stats_out(
    const float* __restrict__ out, float* __restrict__ out_stats)
{
    const int bo = blockIdx.x;
    const float4* src = (const float4*)(out + ((size_t)bo << 14));
    float s1 = 0.f, s2 = 0.f;
    for (int i = threadIdx.x; i < 4096; i += 256) {
        float4 v = src[i];
        s1 += v.x + v.y + v.z + v.w;
        s2 += v.x * v.x + v.y * v.y + v.z * v.z + v.w * v.w;
    }
#pragma unroll
    for (int d = 32; d; d >>= 1) { s1 += __shfl_down(s1, d, 64); s2 += __shfl_down(s2, d, 64); }

    __shared__ float ls1[4], ls2[4];
    const int wv = threadIdx.x >> 6;
    if ((threadIdx.x & 63) == 0) { ls1[wv] = s1; ls2[wv] = s2; }
    __syncthreads();
    if (threadIdx.x == 0) {
        out_stats[bo]       = ls1[0] + ls1[1] + ls1[2] + ls1[3];
        out_stats[256 + bo] = ls2[0] + ls2[1] + ls2[2] + ls2[3];
    }
}

// ---------------------------------------------------------------------------
// Kernel 3: output GroupNorm (16 groups of 4 channels) + ReLU, in place.
// ---------------------------------------------------------------------------
__global__ __launch_bounds__(256) void k_gn_out(
    float* __restrict__ out, const float* __restrict__ out_stats,
    const float* __restrict__ gg, const float* __restrict__ gb)
{
    const float inv_cnt = 1.f / (4.f * 16384.f);
    const int n4 = 1 << 20;
    for (int idx = blockIdx.x * 256 + threadIdx.x; idx < n4; idx += gridDim.x * 256) {
        int flat = idx << 2;
        int ch = (flat >> 14) & 63;
        int b  = flat >> 20;
        int cb = (b << 6) + ((ch >> 2) << 2);
        float s = out_stats[cb] + out_stats[cb + 1] + out_stats[cb + 2] + out_stats[cb + 3];
        float q = out_stats[256 + cb] + out_stats[256 + cb + 1] + out_stats[256 + cb + 2] + out_stats[256 + cb + 3];
        float mu   = s * inv_cnt;
        float istd = rsqrtf(fmaxf(q * inv_cnt - mu * mu, 0.f) + 1e-5f);
        float ga = gg[ch] * istd;
        float be = gb[ch] - mu * ga;
        float4 v = *reinterpret_cast<float4*>(out + flat);
        v.x = fmaxf(fmaf(v.x, ga, be), 0.f);
        v.y = fmaxf(fmaf(v.y, ga, be), 0.f);
        v.z = fmaxf(fmaf(v.z, ga, be), 0.f);
        v.w = fmaxf(fmaf(v.w, ga, be), 0.f);
        *reinterpret_cast<float4*>(out + flat) = v;
    }
}

// ---------------------------------------------------------------------------
extern "C" void kernel_launch(void* const* d_in, const int* in_sizes, int n_in,
                              void* d_out, int out_size, void* d_ws, size_t ws_size,
                              hipStream_t stream)
{
    const float* x       = (const float*)d_in[0];
    const float* w_off   = (const float*)d_in[1];
    const float* b_off   = (const float*)d_in[2];
    const float* w_th    = (const float*)d_in[3];
    const float* b_th    = (const float*)d_in[4];
    const float* g_off   = (const float*)d_in[5];
    const float* be_off  = (const float*)d_in[6];
    const float* g_th    = (const float*)d_in[7];
    const float* be_th   = (const float*)d_in[8];
    const float* w_strip = (const float*)d_in[9];
    const float* b_strip = (const float*)d_in[10];
    const float* gg      = (const float*)d_in[11];
    const float* gb      = (const float*)d_in[12];

    float* out       = (float*)d_out;
    float* ws        = (float*)d_ws;
    float* off_raw   = ws;                      // 589824 floats
    float* th_raw    = ws + 589824;             // 589824 floats
    float* stats     = ws + 1179648;            // 144 floats
    float* out_stats = ws + 1179792;            // 512 floats
    short* w_pack    = (short*)(ws + 1180304);  // 36864 shorts = 18432 floats
    short* xt        = (short*)(ws + 1198736);  // 4194304 shorts = 2097152 floats

    const size_t need_full = (size_t)(1198736 + 2097152) * sizeof(float);
    const bool big = ws_size >= need_full;

    if (big) {
        // k_tr zeroes the accumulation region + transposes + packs weights
        k_tr<<<1024, 256, 0, stream>>>(x, xt, w_strip, w_pack, (float4*)ws);
    } else {
        hipMemsetAsync(ws, 0, (size_t)1180304 * sizeof(float), stream);
        k_pack<<<144, 256, 0, stream>>>(w_strip, w_pack);
    }
    dim3 g1(4, 16, 32);
    k_conv<<<g1, 256, 0, stream>>>(x, w_off, b_off, w_th, b_th, off_raw, th_raw);
    k_stats<<<72, 256, 0, stream>>>(off_raw, th_raw, stats);
    if (big) {
        k_sample_strip3<<<2048, 256, 0, stream>>>(xt, off_raw, th_raw, stats,
                                                  g_off, be_off, g_th, be_th,
                                                  w_pack, b_strip, out, out_stats);
    } else {
        k_sample_strip_old<<<1024, 256, 0, stream>>>(x, off_raw, th_raw, stats,
                                                     g_off, be_off, g_th, be_th,
                                                     w_pack, b_strip, out);
        k_stats_out<<<256, 256, 0, stream>>>(out, out_stats);
    }
    k_gn_out<<<4096, 256, 0, stream>>>(out, out_stats, gg, gb);
}

// Round 13
// 182.679 us; speedup vs baseline: 1.1238x; 1.0059x over previous
//
#include <hip/hip_runtime.h>
#include <math.h>

// Problem constants: B=4, C=64, H=128, W=128, K=9, O=64

typedef short v8s __attribute__((ext_vector_type(8)));
typedef float v4f __attribute__((ext_vector_type(4)));

__device__ __forceinline__ float fast_tanh(float a) {
    float aa = fabsf(a);
    float e = __expf(2.f * aa);
    float t = 1.f - 2.f / (e + 1.f);   // e==inf -> t = 1
    return copysignf(t, a);
}

__device__ __forceinline__ float bf2f(short s) {
    union { unsigned u; float f; } v;
    v.u = ((unsigned)(unsigned short)s) << 16;
    return v.f;
}

// ---------------------------------------------------------------------------
// Pack helper: w_strip -> bf16 A-fragment order.
// w_pack[(((k*4+og)*2+kk)*64 + lane)*8 + j] = bf16( w[(o*64+c)*9+k] )
//   with o = og*16 + (lane&15), c = kk*32 + (lane>>4)*8 + j.
// ---------------------------------------------------------------------------
__device__ __forceinline__ void pack_one(
    const float* __restrict__ w_strip, short* __restrict__ w_pack, int idx)
{
    int j    = idx & 7;
    int lane = (idx >> 3) & 63;
    int kk   = (idx >> 9) & 1;
    int og   = (idx >> 10) & 3;
    int k    = idx >> 12;
    int c = (kk << 5) + ((lane >> 4) << 3) + j;
    int o = (og << 4) + (lane & 15);
    union { short s; __bf16 h; } u;
    u.h = (__bf16)w_strip[(o * 64 + c) * 9 + k];
    w_pack[idx] = u.s;
}

// Standalone pack kernel (fallback path only).
__global__ __launch_bounds__(256) void k_pack(
    const float* __restrict__ w_strip, short* __restrict__ w_pack)
{
    pack_one(w_strip, w_pack, blockIdx.x * 256 + threadIdx.x);
}

// ---------------------------------------------------------------------------
// Kernel 0: NCHW fp32 -> NHWC bf16 transpose of x, with w_pack fused into
// the first 144 blocks AND grid-stride zeroing of the atomic-accumulation
// region (off_raw/th_raw/stats/out_stats) -- replaces the memset dispatch.
// grid 1024 (b * 256 chunks of 64 px), block 256.
// ---------------------------------------------------------------------------
__global__ __launch_bounds__(256) void k_tr(
    const float* __restrict__ x, short* __restrict__ xt,
    const float* __restrict__ w_strip, short* __restrict__ w_pack,
    float4* __restrict__ zbuf)   // 295076 float4 = 1180304 floats
{
    __shared__ float l[64][65];
    const int t    = threadIdx.x;
    const int lane = t & 63;
    const int wv   = t >> 6;
    const int b    = blockIdx.x >> 8;
    const int pix0 = (blockIdx.x & 255) << 6;

    // zero the accumulation region (runs before k_conv on the stream)
    const float4 z4 = {0.f, 0.f, 0.f, 0.f};
    for (int i = blockIdx.x * 256 + t; i < 295076; i += 262144)
        zbuf[i] = z4;

#pragma unroll
    for (int it = 0; it < 16; ++it) {
        int c = (wv << 4) + it;
        l[lane][c] = x[(((size_t)(b << 6) + c) << 14) + pix0 + lane];
    }
    __syncthreads();
    {
        const int p   = t >> 2;
        const int c16 = (t & 3) << 4;
        union { v8s s8; __bf16 hh[8]; } u0, u1;
#pragma unroll
        for (int j = 0; j < 8; ++j) {
            u0.hh[j] = (__bf16)l[p][c16 + j];
            u1.hh[j] = (__bf16)l[p][c16 + 8 + j];
        }
        short* dst = xt + (((size_t)(b << 14) + pix0 + p) << 6) + c16;
        *(v8s*)dst = u0.s8;
        *(v8s*)(dst + 8) = u1.s8;
    }
    // fused w_pack (36864 elements over first 144 blocks)
    if (blockIdx.x < 144)
        pack_one(w_strip, w_pack, blockIdx.x * 256 + t);
}

// ---------------------------------------------------------------------------
// Kernel 1: fused 3x3 conv (off) + 5x5 conv (theta), channel-split 8-way.
// Tile: 32 wide x 8 tall outputs; LDS tile[12][36] (conflict-free window
// reads). Register double-buffer staging with RAW barriers (lgkmcnt only,
// no vmcnt drain). grid (4,16,32): z = b*8+split, 8 blocks/CU resident.
// ---------------------------------------------------------------------------
__global__ __launch_bounds__(256, 8) void k_conv(
    const float* __restrict__ x,
    const float* __restrict__ w_off, const float* __restrict__ b_off,
    const float* __restrict__ w_th,  const float* __restrict__ b_th,
    float* __restrict__ off_raw, float* __restrict__ th_raw)
{
    __shared__ float tile[12][36];
    const int t  = threadIdx.x;
    const int tx = t & 31, ty = t >> 5;
    const int z  = blockIdx.z;
    const int b  = z >> 3, sp = z & 7;
    const int c0 = sp << 3;
    const int h0 = blockIdx.y << 3, w0 = blockIdx.x << 5;

    // hoisted staging geometry (constant across channels)
    const int r1 = t / 36,        cc1 = t - r1 * 36;
    const int e2 = t + 256;
    const int r2 = e2 / 36,       cc2 = e2 - r2 * 36;
    const int hh1 = h0 + r1 - 2,  ww1 = w0 + cc1 - 2;
    const int hh2 = h0 + r2 - 2,  ww2 = w0 + cc2 - 2;
    const bool va1 = (hh1 >= 0 && hh1 < 128 && ww1 >= 0 && ww1 < 128);
    const bool va2 = (t < 176) && (hh2 >= 0 && hh2 < 128 && ww2 >= 0 && ww2 < 128);
    const int of1 = (hh1 << 7) + ww1;
    const int of2 = (hh2 << 7) + ww2;
    const float* xb = x + (((size_t)(b << 6) + c0) << 14);

    float accO[9], accT[9];
#pragma unroll
    for (int k = 0; k < 9; ++k) { accO[k] = 0.f; accT[k] = 0.f; }

    // prologue: issue channel 0 stage loads
    float ra = va1 ? xb[of1] : 0.f;
    float rb = va2 ? xb[of2] : 0.f;

    for (int ci = 0; ci < 8; ++ci) {
        const int c = c0 + ci;
        // barrier 1: previous compute finished reading tile (lgkm only)
        __builtin_amdgcn_sched_barrier(0);
        asm volatile("s_waitcnt lgkmcnt(0)" ::: "memory");
        __builtin_amdgcn_s_barrier();
        __builtin_amdgcn_sched_barrier(0);

        // write staged channel to LDS
        tile[r1][cc1] = ra;
        if (t < 176) tile[r2][cc2] = rb;

        // issue next channel's stage loads (fly across barrier + compute)
        if (ci < 7) {
            const float* xp = xb + ((size_t)(ci + 1) << 14);
            ra = va1 ? xp[of1] : 0.f;
            rb = va2 ? xp[of2] : 0.f;
        }

        // barrier 2: LDS writes visible (lgkm only, vmcnt NOT drained)
        __builtin_amdgcn_sched_barrier(0);
        asm volatile("s_waitcnt lgkmcnt(0)" ::: "memory");
        __builtin_amdgcn_s_barrier();
        __builtin_amdgcn_sched_barrier(0);

        float win[5][5];
#pragma unroll
        for (int i = 0; i < 5; ++i)
#pragma unroll
            for (int j = 0; j < 5; ++j)
                win[i][j] = tile[ty + i][tx + j];

#pragma unroll
        for (int k = 0; k < 9; ++k) {
            const float* wo = w_off + (size_t)((k << 6) + c) * 9;
            float a = accO[k];
#pragma unroll
            for (int i = 0; i < 3; ++i)
#pragma unroll
                for (int j = 0; j < 3; ++j)
                    a = fmaf(win[i + 1][j + 1], wo[i * 3 + j], a);
            accO[k] = a;

            const float* wt = w_th + (size_t)((k << 6) + c) * 25;
            float bb = accT[k];
#pragma unroll
            for (int i = 0; i < 5; ++i)
#pragma unroll
                for (int j = 0; j < 5; ++j)
                    bb = fmaf(win[i][j], wt[i * 5 + j], bb);
            accT[k] = bb;
        }
    }

    const int pix = ((h0 + ty) << 7) + (w0 + tx);
#pragma unroll
    for (int k = 0; k < 9; ++k) {
        float vo = accO[k] + (sp == 0 ? b_off[k] : 0.f);
        float vt = accT[k] + (sp == 0 ? b_th[k]  : 0.f);
        atomicAdd(&off_raw[((b * 9 + k) << 14) + pix], vo);
        atomicAdd(&th_raw [((b * 9 + k) << 14) + pix], vt);
    }
}

// ---------------------------------------------------------------------------
// Kernel 1b: GN stats (sum, sumsq) per (b,k) for off and theta maps.
// ---------------------------------------------------------------------------
__global__ __launch_bounds__(256) void k_stats(
    const float* __restrict__ off_raw, const float* __restrict__ th_raw,
    float* __restrict__ stats)
{
    const int id  = blockIdx.x;          // 0..71
    const int arr = id >= 36;
    const int rem = id - arr * 36;       // b*9+k
    const float4* src = (const float4*)((arr ? th_raw : off_raw) + (rem << 14));

    float s1 = 0.f, s2 = 0.f;
    for (int i = threadIdx.x; i < 4096; i += 256) {
        float4 v = src[i];
        s1 += v.x + v.y + v.z + v.w;
        s2 += v.x * v.x + v.y * v.y + v.z * v.z + v.w * v.w;
    }
#pragma unroll
    for (int d = 32; d; d >>= 1) { s1 += __shfl_down(s1, d, 64); s2 += __shfl_down(s2, d, 64); }

    __shared__ float ls1[4], ls2[4];
    const int wv = threadIdx.x >> 6;
    if ((threadIdx.x & 63) == 0) { ls1[wv] = s1; ls2[wv] = s2; }
    __syncthreads();
    if (threadIdx.x == 0) {
        stats[arr * 72 + rem]      = ls1[0] + ls1[1] + ls1[2] + ls1[3];
        stats[arr * 72 + 36 + rem] = ls2[0] + ls2[1] + ls2[2] + ls2[3];
    }
}

// ---------------------------------------------------------------------------
// Kernel 2: bf16-NHWC gather + MFMA strip contraction, DEPTH-1 pipelined.
// grid 2048 (B * 512 chunks of 32 px), block 256 (4 waves), XCD swizzle.
// Depth-1 (single G buffer, issue k+1 after combining k) needs ~56 VGPR --
// fits the 64-VGPR cap of 8 blocks/CU without spilling (depth-2 at 60+ VGPR
// spilled under any launch_bounds > 4; depth-2 gained nothing over depth-1
// at equal occupancy, so trade pipeline depth for TLP).
// ---------------------------------------------------------------------------
__global__ __launch_bounds__(256, 8) void k_sample_strip3(
    const short* __restrict__ xt,
    const float* __restrict__ off_raw, const float* __restrict__ th_raw,
    const float* __restrict__ stats,
    const float* __restrict__ g_off, const float* __restrict__ be_off,
    const float* __restrict__ g_th,  const float* __restrict__ be_th,
    const short* __restrict__ w_pack, const float* __restrict__ b_strip,
    float* __restrict__ out, float* __restrict__ out_stats)
{
    __shared__ __align__(16) short smem[2][2048];
    const int t    = threadIdx.x;
    const int lane = t & 63;
    const int wv   = __builtin_amdgcn_readfirstlane(t >> 6);
    const int bid  = blockIdx.x;
    const int blk  = ((bid & 7) << 8) + (bid >> 3);   // XCD-chunked swizzle
    const int b    = blk >> 9;
    const int pix0 = (blk & 511) << 5;
    const int l32  = lane & 31;
    const int q    = lane >> 5;
    const int p_img = pix0 + l32;
    const int h    = p_img >> 7, w = p_img & 127;
    const int i15  = lane & 15, lg = lane >> 4;
    const int cg   = (wv << 4) + (q << 3);            // channel base (8 ch)
    const int cb   = (wv << 1) + q;                   // c-block in LDS

    // ---- GN constants (groups 1,2; m in 5..8) ----
    const float inv_cnt = 1.f / (3.f * 16384.f);
    float muO1, isO1, muT1, isT1, muO2, isO2, muT2, isT2;
    {
        float s, qq, mu;
        s = stats[b*9+3] + stats[b*9+4] + stats[b*9+5];
        qq = stats[36+b*9+3] + stats[36+b*9+4] + stats[36+b*9+5];
        mu = s * inv_cnt; muO1 = mu;
        isO1 = rsqrtf(fmaxf(qq * inv_cnt - mu * mu, 0.f) + 1e-5f);
        s = stats[b*9+6] + stats[b*9+7] + stats[b*9+8];
        qq = stats[36+b*9+6] + stats[36+b*9+7] + stats[36+b*9+8];
        mu = s * inv_cnt; muO2 = mu;
        isO2 = rsqrtf(fmaxf(qq * inv_cnt - mu * mu, 0.f) + 1e-5f);
        s = stats[72+b*9+3] + stats[72+b*9+4] + stats[72+b*9+5];
        qq = stats[108+b*9+3] + stats[108+b*9+4] + stats[108+b*9+5];
        mu = s * inv_cnt; muT1 = mu;
        isT1 = rsqrtf(fmaxf(qq * inv_cnt - mu * mu, 0.f) + 1e-5f);
        s = stats[72+b*9+6] + stats[72+b*9+7] + stats[72+b*9+8];
        qq = stats[108+b*9+6] + stats[108+b*9+7] + stats[108+b*9+8];
        mu = s * inv_cnt; muT2 = mu;
        isT2 = rsqrtf(fmaxf(qq * inv_cnt - mu * mu, 0.f) + 1e-5f);
    }

    // ---- per-m deformation params: z (tan), f*cos, f*sin ----
    float zt[4], cyv[4], cxv[4];
#pragma unroll
    for (int m = 5; m <= 8; ++m) {
        const int mi = m - 5;
        float tv = th_raw [((b * 9 + m) << 14) + p_img];
        float ov = off_raw[((b * 9 + m) << 14) + p_img];
        float muT = (m == 5) ? muT1 : muT2, isT = (m == 5) ? isT1 : isT2;
        float muO = (m == 5) ? muO1 : muO2, isO = (m == 5) ? isO1 : isO2;
        float z = (tv - muT) * isT * g_th[m] + be_th[m];
        float f = fast_tanh((ov - muO) * isO * g_off[m] + be_off[m]);
        float r = rsqrtf(1.f + z * z);   // cos(arctan z)
        zt[mi]  = z;
        cyv[mi] = f * r;
        cxv[mi] = z * r * f;
    }

    const short* xtb = xt + ((size_t)b << 20);

    // coords for k != 4 (k==4 handled exactly, no clamp needed)
    auto coords = [&](int k, float& cwy, float& cwx) -> int {
        const int s  = k - 4;
        const int mi = (s < 0 ? -s : s) - 1;
        const float fs = (float)s;
        float yy = (float)h + fs + fs * zt[mi] + cyv[mi];
        float xx = (float)w + 2.f * fs - cxv[mi];
        yy = fminf(fmaxf(yy, 0.f), 127.f);
        xx = fminf(fmaxf(xx, 0.f), 127.f);
        int y0 = min((int)yy, 126), x0 = min((int)xx, 126);
        cwy = yy - (float)y0; cwx = xx - (float)x0;
        return (y0 << 7) + x0;
    };

    v8s G[4];        // depth-1 gather buffer
    v8s Af[2][2];    // A-fragments, double-buffered
    float cwy, cwx, nwy, nwx;

    auto issueG = [&](int k, float& oy, float& ox) {
        if (k == 4) {
            const short* bb = xtb + ((size_t)p_img << 6) + cg;
            G[0] = *(const v8s*)bb;
        } else {
            int cidx = coords(k, oy, ox);
            const short* bb = xtb + ((size_t)cidx << 6) + cg;
            G[0] = *(const v8s*)bb;
            G[1] = *(const v8s*)(bb + 64);
            G[2] = *(const v8s*)(bb + 8192);
            G[3] = *(const v8s*)(bb + 8256);
        }
    };
    auto issueA = [&](int k) {
        const short* wa = w_pack + (((k << 2) + wv) << 10) + (lane << 3);
        Af[k & 1][0] = *(const v8s*)wa;
        Af[k & 1][1] = *(const v8s*)(wa + 512);
    };

    // prologue: fill k=0
    issueG(0, cwy, cwx);
    issueA(0);

    v4f acc[2];
    acc[0] = (v4f)0.f; acc[1] = (v4f)0.f;

#pragma unroll
    for (int k = 0; k < 9; ++k) {
        // 1) combine gathers for k (counted vmcnt wait)
        float vj[8];
        if (k == 4) {
#pragma unroll
            for (int j = 0; j < 8; ++j) vj[j] = bf2f(G[0][j]);
        } else {
#pragma unroll
            for (int j = 0; j < 8; ++j) {
                float c00 = bf2f(G[0][j]), c01 = bf2f(G[1][j]);
                float c10 = bf2f(G[2][j]), c11 = bf2f(G[3][j]);
                float top = fmaf(cwx, c01 - c00, c00);
                float bot = fmaf(cwx, c11 - c10, c10);
                vj[j] = fmaf(cwy, bot - top, top);
            }
        }

        // 2) issue gathers + A-frags for k+1 (fly across barrier + MFMA)
        if (k < 8) {
            issueG(k + 1, nwy, nwx);
            issueA(k + 1);
        }

        // 3) pack bf16 B-chunk, write LDS
        union { v8s s8; __bf16 hh[8]; } u;
#pragma unroll
        for (int j = 0; j < 8; ++j) u.hh[j] = (__bf16)vj[j];
        *(v8s*)&smem[k & 1][((cb << 5) + l32) << 3] = u.s8;

        // 4) raw barrier: wait LDS ops only, do NOT drain vmcnt
        __builtin_amdgcn_sched_barrier(0);
        asm volatile("s_waitcnt lgkmcnt(0)" ::: "memory");
        __builtin_amdgcn_s_barrier();
        __builtin_amdgcn_sched_barrier(0);

        // 5) MFMA; setprio around the MFMA cluster (T5)
        __builtin_amdgcn_s_setprio(1);
#pragma unroll
        for (int n = 0; n < 2; ++n) {
            int p16 = (n << 4) + i15;
            v8s b0 = *(const v8s*)&smem[k & 1][((lg << 5) + p16) << 3];
            v8s b1 = *(const v8s*)&smem[k & 1][(((lg + 4) << 5) + p16) << 3];
            acc[n] = __builtin_amdgcn_mfma_f32_16x16x32_bf16(Af[k & 1][0], b0, acc[n], 0, 0, 0);
            acc[n] = __builtin_amdgcn_mfma_f32_16x16x32_bf16(Af[k & 1][1], b1, acc[n], 0, 0, 0);
        }
        __builtin_amdgcn_s_setprio(0);

        cwy = nwy; cwx = nwx;
    }

    // epilogue: D col=lane&15 (pixel), row=(lane>>4)*4+reg (o) + fused GN stats
#pragma unroll
    for (int r = 0; r < 4; ++r) {
        int o = (wv << 4) + (lg << 2) + r;
        float bias = b_strip[o];
        float v0 = acc[0][r] + bias;
        float v1 = acc[1][r] + bias;
        float* op = out + (((size_t)(b << 6) + o) << 14) + pix0 + i15;
        op[0]  = v0;
        op[16] = v1;
        float s1 = v0 + v1;
        float s2 = v0 * v0 + v1 * v1;
#pragma unroll
        for (int d = 1; d <= 8; d <<= 1) {
            s1 += __shfl_xor(s1, d, 64);
            s2 += __shfl_xor(s2, d, 64);
        }
        if (i15 == 0) {
            atomicAdd(&out_stats[(b << 6) + o], s1);
            atomicAdd(&out_stats[256 + (b << 6) + o], s2);
        }
    }
}

// ---------------------------------------------------------------------------
// Kernel 2 (OLD fallback, NCHW fp32 gather): used when ws can't hold xt.
// ---------------------------------------------------------------------------
__global__ __launch_bounds__(256) void k_sample_strip_old(
    const float* __restrict__ x,
    const float* __restrict__ off_raw, const float* __restrict__ th_raw,
    const float* __restrict__ stats,
    const float* __restrict__ g_off, const float* __restrict__ be_off,
    const float* __restrict__ g_th,  const float* __restrict__ be_th,
    const short* __restrict__ w_pack, const float* __restrict__ b_strip,
    float* __restrict__ out)
{
    __shared__ __align__(16) short smem[64 * 64];
    const int t    = threadIdx.x;
    const int lane = t & 63;
    const int wv   = __builtin_amdgcn_readfirstlane(t >> 6);
    const int bid  = blockIdx.x;
    const int blk  = ((bid & 7) << 7) + (bid >> 3);
    const int b    = blk >> 8;
    const int pix0 = (blk & 255) << 6;
    const int p    = pix0 + lane;
    const int h    = p >> 7, w = p & 127;
    const int i15  = lane & 15, lg = lane >> 4;

    float muO[3], isO[3], muT[3], isT[3];
    const float inv_cnt = 1.f / (3.f * 16384.f);
#pragma unroll
    for (int g = 0; g < 3; ++g) {
        float s = 0.f, q = 0.f;
#pragma unroll
        for (int j = 0; j < 3; ++j) { s += stats[b * 9 + 3 * g + j]; q += stats[36 + b * 9 + 3 * g + j]; }
        float mu = s * inv_cnt;
        muO[g] = mu; isO[g] = rsqrtf(fmaxf(q * inv_cnt - mu * mu, 0.f) + 1e-5f);
        s = 0.f; q = 0.f;
#pragma unroll
        for (int j = 0; j < 3; ++j) { s += stats[72 + b * 9 + 3 * g + j]; q += stats[108 + b * 9 + 3 * g + j]; }
        mu = s * inv_cnt;
        muT[g] = mu; isT[g] = rsqrtf(fmaxf(q * inv_cnt - mu * mu, 0.f) + 1e-5f);
    }

    const float* xb = x + ((size_t)((b << 6) + (wv << 4)) << 14);
    v4f acc[4];
#pragma unroll
    for (int n = 0; n < 4; ++n) acc[n] = (v4f)0.f;

    for (int k = 0; k < 9; ++k) {
        float v[16];
        if (k == 4) {
#pragma unroll
            for (int ci = 0; ci < 16; ++ci) v[ci] = xb[(ci << 14) + p];
        } else {
            const int s = k - 4;
            const int m = 4 + (s < 0 ? -s : s);
            const int g = m / 3;
            float z = (th_raw[((b * 9 + m) << 14) + p] - muT[g]) * isT[g] * g_th[m] + be_th[m];
            float f = fast_tanh((off_raw[((b * 9 + m) << 14) + p] - muO[g]) * isO[g] * g_off[m] + be_off[m]);
            float r = rsqrtf(1.f + z * z);
            float fs = (float)s;
            float yy = (float)h + fs + fs * z + f * r;
            float xx = (float)w + fs + fs - z * r * f;
            yy = fminf(fmaxf(yy, 0.f), 127.f);
            xx = fminf(fmaxf(xx, 0.f), 127.f);
            int y0 = min((int)yy, 126);
            int x0 = min((int)xx, 126);
            float wy = yy - (float)y0;
            float wx = xx - (float)x0;
            const float* base = xb + (y0 << 7) + x0;
#pragma unroll
            for (int ci = 0; ci < 16; ++ci) {
                const float* qp = base + (ci << 14);
                float2 r0 = *(const float2*)qp;
                float2 r1 = *(const float2*)(qp + 128);
                float lo = fmaf(wx, r0.y - r0.x, r0.x);
                float hi = fmaf(wx, r1.y - r1.x, r1.x);
                v[ci] = fmaf(wy, hi - lo, lo);
            }
        }

        union { v8s s8; __bf16 hh[8]; } u0, u1;
#pragma unroll
        for (int ci = 0; ci < 8; ++ci) { u0.hh[ci] = (__bf16)v[ci]; u1.hh[ci] = (__bf16)v[ci + 8]; }
        *(v8s*)&smem[(lane << 6) + ((((wv << 1) + 0) + lane) & 7) * 8] = u0.s8;
        *(v8s*)&smem[(lane << 6) + ((((wv << 1) + 1) + lane) & 7) * 8] = u1.s8;
        __syncthreads();

        const short* wpk = w_pack + (((k << 2) + wv) << 10) + (lane << 3);
        v8s a0 = *(const v8s*)wpk;
        v8s a1 = *(const v8s*)(wpk + 512);

#pragma unroll
        for (int n = 0; n < 4; ++n) {
            int r = (n << 4) + i15;
            v8s b0 = *(const v8s*)&smem[(r << 6) + (((lg    ) + r) & 7) * 8];
            v8s b1 = *(const v8s*)&smem[(r << 6) + (((lg + 4) + r) & 7) * 8];
            acc[n] = __builtin_amdgcn_mfma_f32_16x16x32_bf16(a0, b0, acc[n], 0, 0, 0);
            acc[n] = __builtin_amdgcn_mfma_f32_16x16x32_bf16(a1, b1, acc[n], 0, 0, 0);
        }
        __syncthreads();
    }

#pragma unroll
    for (int r = 0; r < 4; ++r) {
        int o = (wv << 4) + (lg << 2) + r;
        float bias = b_strip[o];
        float* op = out + ((size_t)((b << 6) + o) << 14) + pix0 + i15;
#pragma unroll
        for (int n = 0; n < 4; ++n)
            op[n << 4] = acc[n][r] + bias;
    }
}

// ---------------------------------------------------------------------------
// Kernel 2b: output GN stats per (b,o). grid 256. (fallback path only)
// ---------------------------------------------------------------------------
__global__ __launch_bounds__(256) void k_stats_out(
    const float* __restrict__ out, float* __restrict__ out_stats)
{
    const int bo = blockIdx.x;
    const float4* src = (const float4*)(out + ((size_t)bo << 14));
    float s1 = 0.f, s2 = 0.f;
    for (int i = threadIdx.x; i < 4096; i += 256) {
        float4 v = src[i];
        s1 += v.x + v.y + v.z + v.w;
        s2 += v.x * v.x + v.y * v.y + v.z * v.z + v.w * v.w;
    }
#pragma unroll
    for (int d = 32; d; d >>= 1) { s1 += __shfl_down(s1, d, 64); s2 += __shfl_down(s2, d, 64); }

    __shared__ float ls1[4], ls2[4];
    const int wv = threadIdx.x >> 6;
    if ((threadIdx.x & 63) == 0) { ls1[wv] = s1; ls2[wv] = s2; }
    __syncthreads();
    if (threadIdx.x == 0) {
        out_stats[bo]       = ls1[0] + ls1[1] + ls1[2] + ls1[3];
        out_stats[256 + bo] = ls2[0] + ls2[1] + ls2[2] + ls2[3];
    }
}

// ---------------------------------------------------------------------------
// Kernel 3: output GroupNorm (16 groups of 4 channels) + ReLU, in place.
// ---------------------------------------------------------------------------
__global__ __launch_bounds__(256) void k_gn_out(
    float* __restrict__ out, const float* __restrict__ out_stats,
    const float* __restrict__ gg, const float* __restrict__ gb)
{
    const float inv_cnt = 1.f / (4.f * 16384.f);
    const int n4 = 1 << 20;
    for (int idx = blockIdx.x * 256 + threadIdx.x; idx < n4; idx += gridDim.x * 256) {
        int flat = idx << 2;
        int ch = (flat >> 14) & 63;
        int b  = flat >> 20;
        int cb = (b << 6) + ((ch >> 2) << 2);
        float s = out_stats[cb] + out_stats[cb + 1] + out_stats[cb + 2] + out_stats[cb + 3];
        float q = out_stats[256 + cb] + out_stats[256 + cb + 1] + out_stats[256 + cb + 2] + out_stats[256 + cb + 3];
        float mu   = s * inv_cnt;
        float istd = rsqrtf(fmaxf(q * inv_cnt - mu * mu, 0.f) + 1e-5f);
        float ga = gg[ch] * istd;
        float be = gb[ch] - mu * ga;
        float4 v = *reinterpret_cast<float4*>(out + flat);
        v.x = fmaxf(fmaf(v.x, ga, be), 0.f);
        v.y = fmaxf(fmaf(v.y, ga, be), 0.f);
        v.z = fmaxf(fmaf(v.z, ga, be), 0.f);
        v.w = fmaxf(fmaf(v.w, ga, be), 0.f);
        *reinterpret_cast<float4*>(out + flat) = v;
    }
}

// ---------------------------------------------------------------------------
extern "C" void kernel_launch(void* const* d_in, const int* in_sizes, int n_in,
                              void* d_out, int out_size, void* d_ws, size_t ws_size,
                              hipStream_t stream)
{
    const float* x       = (const float*)d_in[0];
    const float* w_off   = (const float*)d_in[1];
    const float* b_off   = (const float*)d_in[2];
    const float* w_th    = (const float*)d_in[3];
    const float* b_th    = (const float*)d_in[4];
    const float* g_off   = (const float*)d_in[5];
    const float* be_off  = (const float*)d_in[6];
    const float* g_th    = (const float*)d_in[7];
    const float* be_th   = (const float*)d_in[8];
    const float* w_strip = (const float*)d_in[9];
    const float* b_strip = (const float*)d_in[10];
    const float* gg      = (const float*)d_in[11];
    const float* gb      = (const float*)d_in[12];

    float* out       = (float*)d_out;
    float* ws        = (float*)d_ws;
    float* off_raw   = ws;                      // 589824 floats
    float* th_raw    = ws + 589824;             // 589824 floats
    float* stats     = ws + 1179648;            // 144 floats
    float* out_stats = ws + 1179792;            // 512 floats
    short* w_pack    = (short*)(ws + 1180304);  // 36864 shorts = 18432 floats
    short* xt        = (short*)(ws + 1198736);  // 4194304 shorts = 2097152 floats

    const size_t need_full = (size_t)(1198736 + 2097152) * sizeof(float);
    const bool big = ws_size >= need_full;

    if (big) {
        // k_tr zeroes the accumulation region + transposes + packs weights
        k_tr<<<1024, 256, 0, stream>>>(x, xt, w_strip, w_pack, (float4*)ws);
    } else {
        hipMemsetAsync(ws, 0, (size_t)1180304 * sizeof(float), stream);
        k_pack<<<144, 256, 0, stream>>>(w_strip, w_pack);
    }
    dim3 g1(4, 16, 32);
    k_conv<<<g1, 256, 0, stream>>>(x, w_off, b_off, w_th, b_th, off_raw, th_raw);
    k_stats<<<72, 256, 0, stream>>>(off_raw, th_raw, stats);
    if (big) {
        k_sample_strip3<<<2048, 256, 0, stream>>>(xt, off_raw, th_raw, stats,
                                                  g_off, be_off, g_th, be_th,
                                                  w_pack, b_strip, out, out_stats);
    } else {
        k_sample_strip_old<<<1024, 256, 0, stream>>>(x, off_raw, th_raw, stats,
                                                     g_off, be_off, g_th, be_th,
                                                     w_pack, b_strip, out);
        k_stats_out<<<256, 256, 0, stream>>>(out, out_stats);
    }
    k_gn_out<<<4096, 256, 0, stream>>>(out, out_stats, gg, gb);
}

// Round 14
// 166.958 us; speedup vs baseline: 1.2296x; 1.0942x over previous
//
#include <hip/hip_runtime.h>
#include <math.h>

// Problem constants: B=4, C=64, H=128, W=128, K=9, O=64

typedef short v8s __attribute__((ext_vector_type(8)));
typedef float v4f __attribute__((ext_vector_type(4)));

__device__ __forceinline__ float fast_tanh(float a) {
    float aa = fabsf(a);
    float e = __expf(2.f * aa);
    float t = 1.f - 2.f / (e + 1.f);   // e==inf -> t = 1
    return copysignf(t, a);
}

__device__ __forceinline__ float bf2f(short s) {
    union { unsigned u; float f; } v;
    v.u = ((unsigned)(unsigned short)s) << 16;
    return v.f;
}

// ---------------------------------------------------------------------------
// Pack helper: w_strip -> bf16 A-fragment order.
// ---------------------------------------------------------------------------
__device__ __forceinline__ void pack_one(
    const float* __restrict__ w_strip, short* __restrict__ w_pack, int idx)
{
    int j    = idx & 7;
    int lane = (idx >> 3) & 63;
    int kk   = (idx >> 9) & 1;
    int og   = (idx >> 10) & 3;
    int k    = idx >> 12;
    int c = (kk << 5) + ((lane >> 4) << 3) + j;
    int o = (og << 4) + (lane & 15);
    union { short s; __bf16 h; } u;
    u.h = (__bf16)w_strip[(o * 64 + c) * 9 + k];
    w_pack[idx] = u.s;
}

// Standalone pack kernel (fallback path only).
__global__ __launch_bounds__(256) void k_pack(
    const float* __restrict__ w_strip, short* __restrict__ w_pack)
{
    pack_one(w_strip, w_pack, blockIdx.x * 256 + threadIdx.x);
}

// ---------------------------------------------------------------------------
// Kernel 0: NCHW fp32 -> NHWC bf16 transpose + fused w_pack + zeroing.
// grid 1024 (b * 256 chunks of 64 px), block 256.
// ---------------------------------------------------------------------------
__global__ __launch_bounds__(256) void k_tr(
    const float* __restrict__ x, short* __restrict__ xt,
    const float* __restrict__ w_strip, short* __restrict__ w_pack,
    float4* __restrict__ zbuf)   // 295076 float4 = 1180304 floats
{
    __shared__ float l[64][65];
    const int t    = threadIdx.x;
    const int lane = t & 63;
    const int wv   = t >> 6;
    const int b    = blockIdx.x >> 8;
    const int pix0 = (blockIdx.x & 255) << 6;

    const float4 z4 = {0.f, 0.f, 0.f, 0.f};
    for (int i = blockIdx.x * 256 + t; i < 295076; i += 262144)
        zbuf[i] = z4;

#pragma unroll
    for (int it = 0; it < 16; ++it) {
        int c = (wv << 4) + it;
        l[lane][c] = x[(((size_t)(b << 6) + c) << 14) + pix0 + lane];
    }
    __syncthreads();
    {
        const int p   = t >> 2;
        const int c16 = (t & 3) << 4;
        union { v8s s8; __bf16 hh[8]; } u0, u1;
#pragma unroll
        for (int j = 0; j < 8; ++j) {
            u0.hh[j] = (__bf16)l[p][c16 + j];
            u1.hh[j] = (__bf16)l[p][c16 + 8 + j];
        }
        short* dst = xt + (((size_t)(b << 14) + pix0 + p) << 6) + c16;
        *(v8s*)dst = u0.s8;
        *(v8s*)(dst + 8) = u1.s8;
    }
    if (blockIdx.x < 144)
        pack_one(w_strip, w_pack, blockIdx.x * 256 + t);
}

// ---------------------------------------------------------------------------
// Kernel 1: fused 3x3 conv (off) + 5x5 conv (theta), channel-split 8-way.
// grid (4,16,32): z = b*8+split, 8 blocks/CU resident. [round-12 proven]
// ---------------------------------------------------------------------------
__global__ __launch_bounds__(256, 8) void k_conv(
    const float* __restrict__ x,
    const float* __restrict__ w_off, const float* __restrict__ b_off,
    const float* __restrict__ w_th,  const float* __restrict__ b_th,
    float* __restrict__ off_raw, float* __restrict__ th_raw)
{
    __shared__ float tile[12][36];
    const int t  = threadIdx.x;
    const int tx = t & 31, ty = t >> 5;
    const int z  = blockIdx.z;
    const int b  = z >> 3, sp = z & 7;
    const int c0 = sp << 3;
    const int h0 = blockIdx.y << 3, w0 = blockIdx.x << 5;

    const int r1 = t / 36,        cc1 = t - r1 * 36;
    const int e2 = t + 256;
    const int r2 = e2 / 36,       cc2 = e2 - r2 * 36;
    const int hh1 = h0 + r1 - 2,  ww1 = w0 + cc1 - 2;
    const int hh2 = h0 + r2 - 2,  ww2 = w0 + cc2 - 2;
    const bool va1 = (hh1 >= 0 && hh1 < 128 && ww1 >= 0 && ww1 < 128);
    const bool va2 = (t < 176) && (hh2 >= 0 && hh2 < 128 && ww2 >= 0 && ww2 < 128);
    const int of1 = (hh1 << 7) + ww1;
    const int of2 = (hh2 << 7) + ww2;
    const float* xb = x + (((size_t)(b << 6) + c0) << 14);

    float accO[9], accT[9];
#pragma unroll
    for (int k = 0; k < 9; ++k) { accO[k] = 0.f; accT[k] = 0.f; }

    float ra = va1 ? xb[of1] : 0.f;
    float rb = va2 ? xb[of2] : 0.f;

    for (int ci = 0; ci < 8; ++ci) {
        const int c = c0 + ci;
        __builtin_amdgcn_sched_barrier(0);
        asm volatile("s_waitcnt lgkmcnt(0)" ::: "memory");
        __builtin_amdgcn_s_barrier();
        __builtin_amdgcn_sched_barrier(0);

        tile[r1][cc1] = ra;
        if (t < 176) tile[r2][cc2] = rb;

        if (ci < 7) {
            const float* xp = xb + ((size_t)(ci + 1) << 14);
            ra = va1 ? xp[of1] : 0.f;
            rb = va2 ? xp[of2] : 0.f;
        }

        __builtin_amdgcn_sched_barrier(0);
        asm volatile("s_waitcnt lgkmcnt(0)" ::: "memory");
        __builtin_amdgcn_s_barrier();
        __builtin_amdgcn_sched_barrier(0);

        float win[5][5];
#pragma unroll
        for (int i = 0; i < 5; ++i)
#pragma unroll
            for (int j = 0; j < 5; ++j)
                win[i][j] = tile[ty + i][tx + j];

#pragma unroll
        for (int k = 0; k < 9; ++k) {
            const float* wo = w_off + (size_t)((k << 6) + c) * 9;
            float a = accO[k];
#pragma unroll
            for (int i = 0; i < 3; ++i)
#pragma unroll
                for (int j = 0; j < 3; ++j)
                    a = fmaf(win[i + 1][j + 1], wo[i * 3 + j], a);
            accO[k] = a;

            const float* wt = w_th + (size_t)((k << 6) + c) * 25;
            float bb = accT[k];
#pragma unroll
            for (int i = 0; i < 5; ++i)
#pragma unroll
                for (int j = 0; j < 5; ++j)
                    bb = fmaf(win[i][j], wt[i * 5 + j], bb);
            accT[k] = bb;
        }
    }

    const int pix = ((h0 + ty) << 7) + (w0 + tx);
#pragma unroll
    for (int k = 0; k < 9; ++k) {
        float vo = accO[k] + (sp == 0 ? b_off[k] : 0.f);
        float vt = accT[k] + (sp == 0 ? b_th[k]  : 0.f);
        atomicAdd(&off_raw[((b * 9 + k) << 14) + pix], vo);
        atomicAdd(&th_raw [((b * 9 + k) << 14) + pix], vt);
    }
}

// ---------------------------------------------------------------------------
// Kernel 1b: GN stats (sum, sumsq) per (b,k) for off and theta maps.
// ---------------------------------------------------------------------------
__global__ __launch_bounds__(256) void k_stats(
    const float* __restrict__ off_raw, const float* __restrict__ th_raw,
    float* __restrict__ stats)
{
    const int id  = blockIdx.x;          // 0..71
    const int arr = id >= 36;
    const int rem = id - arr * 36;       // b*9+k
    const float4* src = (const float4*)((arr ? th_raw : off_raw) + (rem << 14));

    float s1 = 0.f, s2 = 0.f;
    for (int i = threadIdx.x; i < 4096; i += 256) {
        float4 v = src[i];
        s1 += v.x + v.y + v.z + v.w;
        s2 += v.x * v.x + v.y * v.y + v.z * v.z + v.w * v.w;
    }
#pragma unroll
    for (int d = 32; d; d >>= 1) { s1 += __shfl_down(s1, d, 64); s2 += __shfl_down(s2, d, 64); }

    __shared__ float ls1[4], ls2[4];
    const int wv = threadIdx.x >> 6;
    if ((threadIdx.x & 63) == 0) { ls1[wv] = s1; ls2[wv] = s2; }
    __syncthreads();
    if (threadIdx.x == 0) {
        stats[arr * 72 + rem]      = ls1[0] + ls1[1] + ls1[2] + ls1[3];
        stats[arr * 72 + 36 + rem] = ls2[0] + ls2[1] + ls2[2] + ls2[3];
    }
}

// ---------------------------------------------------------------------------
// Kernel 2: bf16-NHWC gather + MFMA strip contraction, DEPTH-1 pipelined.
// grid 2048 (B * 512 chunks of 32 px), block 256 (4 waves), XCD swizzle.
// launch_bounds (256,6): cap ~85 VGPR >= depth-1's ~72-75 need -> no spill
// (tested: (256,8) cap64 spills depth-1; (256,6) cap85 spills depth-2;
//  this is the one spill-free point above 4 blocks/CU).
// ---------------------------------------------------------------------------
__global__ __launch_bounds__(256, 6) void k_sample_strip3(
    const short* __restrict__ xt,
    const float* __restrict__ off_raw, const float* __restrict__ th_raw,
    const float* __restrict__ stats,
    const float* __restrict__ g_off, const float* __restrict__ be_off,
    const float* __restrict__ g_th,  const float* __restrict__ be_th,
    const short* __restrict__ w_pack, const float* __restrict__ b_strip,
    float* __restrict__ out, float* __restrict__ out_stats)
{
    __shared__ __align__(16) short smem[2][2048];
    const int t    = threadIdx.x;
    const int lane = t & 63;
    const int wv   = __builtin_amdgcn_readfirstlane(t >> 6);
    const int bid  = blockIdx.x;
    const int blk  = ((bid & 7) << 8) + (bid >> 3);   // XCD-chunked swizzle
    const int b    = blk >> 9;
    const int pix0 = (blk & 511) << 5;
    const int l32  = lane & 31;
    const int q    = lane >> 5;
    const int p_img = pix0 + l32;
    const int h    = p_img >> 7, w = p_img & 127;
    const int i15  = lane & 15, lg = lane >> 4;
    const int cg   = (wv << 4) + (q << 3);            // channel base (8 ch)
    const int cb   = (wv << 1) + q;                   // c-block in LDS

    // ---- GN constants (groups 1,2; m in 5..8) ----
    const float inv_cnt = 1.f / (3.f * 16384.f);
    float muO1, isO1, muT1, isT1, muO2, isO2, muT2, isT2;
    {
        float s, qq, mu;
        s = stats[b*9+3] + stats[b*9+4] + stats[b*9+5];
        qq = stats[36+b*9+3] + stats[36+b*9+4] + stats[36+b*9+5];
        mu = s * inv_cnt; muO1 = mu;
        isO1 = rsqrtf(fmaxf(qq * inv_cnt - mu * mu, 0.f) + 1e-5f);
        s = stats[b*9+6] + stats[b*9+7] + stats[b*9+8];
        qq = stats[36+b*9+6] + stats[36+b*9+7] + stats[36+b*9+8];
        mu = s * inv_cnt; muO2 = mu;
        isO2 = rsqrtf(fmaxf(qq * inv_cnt - mu * mu, 0.f) + 1e-5f);
        s = stats[72+b*9+3] + stats[72+b*9+4] + stats[72+b*9+5];
        qq = stats[108+b*9+3] + stats[108+b*9+4] + stats[108+b*9+5];
        mu = s * inv_cnt; muT1 = mu;
        isT1 = rsqrtf(fmaxf(qq * inv_cnt - mu * mu, 0.f) + 1e-5f);
        s = stats[72+b*9+6] + stats[72+b*9+7] + stats[72+b*9+8];
        qq = stats[108+b*9+6] + stats[108+b*9+7] + stats[108+b*9+8];
        mu = s * inv_cnt; muT2 = mu;
        isT2 = rsqrtf(fmaxf(qq * inv_cnt - mu * mu, 0.f) + 1e-5f);
    }

    // ---- per-m deformation params: z (tan), f*cos, f*sin ----
    float zt[4], cyv[4], cxv[4];
#pragma unroll
    for (int m = 5; m <= 8; ++m) {
        const int mi = m - 5;
        float tv = th_raw [((b * 9 + m) << 14) + p_img];
        float ov = off_raw[((b * 9 + m) << 14) + p_img];
        float muT = (m == 5) ? muT1 : muT2, isT = (m == 5) ? isT1 : isT2;
        float muO = (m == 5) ? muO1 : muO2, isO = (m == 5) ? isO1 : isO2;
        float z = (tv - muT) * isT * g_th[m] + be_th[m];
        float f = fast_tanh((ov - muO) * isO * g_off[m] + be_off[m]);
        float r = rsqrtf(1.f + z * z);   // cos(arctan z)
        zt[mi]  = z;
        cyv[mi] = f * r;
        cxv[mi] = z * r * f;
    }

    const short* xtb = xt + ((size_t)b << 20);

    // coords for k != 4 (k==4 handled exactly, no clamp needed)
    auto coords = [&](int k, float& cwy, float& cwx) -> int {
        const int s  = k - 4;
        const int mi = (s < 0 ? -s : s) - 1;
        const float fs = (float)s;
        float yy = (float)h + fs + fs * zt[mi] + cyv[mi];
        float xx = (float)w + 2.f * fs - cxv[mi];
        yy = fminf(fmaxf(yy, 0.f), 127.f);
        xx = fminf(fmaxf(xx, 0.f), 127.f);
        int y0 = min((int)yy, 126), x0 = min((int)xx, 126);
        cwy = yy - (float)y0; cwx = xx - (float)x0;
        return (y0 << 7) + x0;
    };

    v8s G[4];        // depth-1 gather buffer
    v8s Af[2][2];    // A-fragments, double-buffered
    float cwy, cwx, nwy, nwx;

    auto issueG = [&](int k, float& oy, float& ox) {
        if (k == 4) {
            const short* bb = xtb + ((size_t)p_img << 6) + cg;
            G[0] = *(const v8s*)bb;
        } else {
            int cidx = coords(k, oy, ox);
            const short* bb = xtb + ((size_t)cidx << 6) + cg;
            G[0] = *(const v8s*)bb;
            G[1] = *(const v8s*)(bb + 64);
            G[2] = *(const v8s*)(bb + 8192);
            G[3] = *(const v8s*)(bb + 8256);
        }
    };
    auto issueA = [&](int k) {
        const short* wa = w_pack + (((k << 2) + wv) << 10) + (lane << 3);
        Af[k & 1][0] = *(const v8s*)wa;
        Af[k & 1][1] = *(const v8s*)(wa + 512);
    };

    // prologue: fill k=0
    issueG(0, cwy, cwx);
    issueA(0);

    v4f acc[2];
    acc[0] = (v4f)0.f; acc[1] = (v4f)0.f;

#pragma unroll
    for (int k = 0; k < 9; ++k) {
        // 1) combine gathers for k (counted vmcnt wait)
        float vj[8];
        if (k == 4) {
#pragma unroll
            for (int j = 0; j < 8; ++j) vj[j] = bf2f(G[0][j]);
        } else {
#pragma unroll
            for (int j = 0; j < 8; ++j) {
                float c00 = bf2f(G[0][j]), c01 = bf2f(G[1][j]);
                float c10 = bf2f(G[2][j]), c11 = bf2f(G[3][j]);
                float top = fmaf(cwx, c01 - c00, c00);
                float bot = fmaf(cwx, c11 - c10, c10);
                vj[j] = fmaf(cwy, bot - top, top);
            }
        }

        // 2) issue gathers + A-frags for k+1 (fly across barrier + MFMA)
        if (k < 8) {
            issueG(k + 1, nwy, nwx);
            issueA(k + 1);
        }

        // 3) pack bf16 B-chunk, write LDS
        union { v8s s8; __bf16 hh[8]; } u;
#pragma unroll
        for (int j = 0; j < 8; ++j) u.hh[j] = (__bf16)vj[j];
        *(v8s*)&smem[k & 1][((cb << 5) + l32) << 3] = u.s8;

        // 4) raw barrier: wait LDS ops only, do NOT drain vmcnt
        __builtin_amdgcn_sched_barrier(0);
        asm volatile("s_waitcnt lgkmcnt(0)" ::: "memory");
        __builtin_amdgcn_s_barrier();
        __builtin_amdgcn_sched_barrier(0);

        // 5) MFMA; setprio around the MFMA cluster (T5)
        __builtin_amdgcn_s_setprio(1);
#pragma unroll
        for (int n = 0; n < 2; ++n) {
            int p16 = (n << 4) + i15;
            v8s b0 = *(const v8s*)&smem[k & 1][((lg << 5) + p16) << 3];
            v8s b1 = *(const v8s*)&smem[k & 1][(((lg + 4) << 5) + p16) << 3];
            acc[n] = __builtin_amdgcn_mfma_f32_16x16x32_bf16(Af[k & 1][0], b0, acc[n], 0, 0, 0);
            acc[n] = __builtin_amdgcn_mfma_f32_16x16x32_bf16(Af[k & 1][1], b1, acc[n], 0, 0, 0);
        }
        __builtin_amdgcn_s_setprio(0);

        cwy = nwy; cwx = nwx;
    }

    // epilogue: D col=lane&15 (pixel), row=(lane>>4)*4+reg (o) + fused GN stats
#pragma unroll
    for (int r = 0; r < 4; ++r) {
        int o = (wv << 4) + (lg << 2) + r;
        float bias = b_strip[o];
        float v0 = acc[0][r] + bias;
        float v1 = acc[1][r] + bias;
        float* op = out + (((size_t)(b << 6) + o) << 14) + pix0 + i15;
        op[0]  = v0;
        op[16] = v1;
        float s1 = v0 + v1;
        float s2 = v0 * v0 + v1 * v1;
#pragma unroll
        for (int d = 1; d <= 8; d <<= 1) {
            s1 += __shfl_xor(s1, d, 64);
            s2 += __shfl_xor(s2, d, 64);
        }
        if (i15 == 0) {
            atomicAdd(&out_stats[(b << 6) + o], s1);
            atomicAdd(&out_stats[256 + (b << 6) + o], s2);
        }
    }
}

// ---------------------------------------------------------------------------
// Kernel 2 (OLD fallback, NCHW fp32 gather): used when ws can't hold xt.
// ---------------------------------------------------------------------------
__global__ __launch_bounds__(256) void k_sample_strip_old(
    const float* __restrict__ x,
    const float* __restrict__ off_raw, const float* __restrict__ th_raw,
    const float* __restrict__ stats,
    const float* __restrict__ g_off, const float* __restrict__ be_off,
    const float* __restrict__ g_th,  const float* __restrict__ be_th,
    const short* __restrict__ w_pack, const float* __restrict__ b_strip,
    float* __restrict__ out)
{
    __shared__ __align__(16) short smem[64 * 64];
    const int t    = threadIdx.x;
    const int lane = t & 63;
    const int wv   = __builtin_amdgcn_readfirstlane(t >> 6);
    const int bid  = blockIdx.x;
    const int blk  = ((bid & 7) << 7) + (bid >> 3);
    const int b    = blk >> 8;
    const int pix0 = (blk & 255) << 6;
    const int p    = pix0 + lane;
    const int h    = p >> 7, w = p & 127;
    const int i15  = lane & 15, lg = lane >> 4;

    float muO[3], isO[3], muT[3], isT[3];
    const float inv_cnt = 1.f / (3.f * 16384.f);
#pragma unroll
    for (int g = 0; g < 3; ++g) {
        float s = 0.f, q = 0.f;
#pragma unroll
        for (int j = 0; j < 3; ++j) { s += stats[b * 9 + 3 * g + j]; q += stats[36 + b * 9 + 3 * g + j]; }
        float mu = s * inv_cnt;
        muO[g] = mu; isO[g] = rsqrtf(fmaxf(q * inv_cnt - mu * mu, 0.f) + 1e-5f);
        s = 0.f; q = 0.f;
#pragma unroll
        for (int j = 0; j < 3; ++j) { s += stats[72 + b * 9 + 3 * g + j]; q += stats[108 + b * 9 + 3 * g + j]; }
        mu = s * inv_cnt;
        muT[g] = mu; isT[g] = rsqrtf(fmaxf(q * inv_cnt - mu * mu, 0.f) + 1e-5f);
    }

    const float* xb = x + ((size_t)((b << 6) + (wv << 4)) << 14);
    v4f acc[4];
#pragma unroll
    for (int n = 0; n < 4; ++n) acc[n] = (v4f)0.f;

    for (int k = 0; k < 9; ++k) {
        float v[16];
        if (k == 4) {
#pragma unroll
            for (int ci = 0; ci < 16; ++ci) v[ci] = xb[(ci << 14) + p];
        } else {
            const int s = k - 4;
            const int m = 4 + (s < 0 ? -s : s);
            const int g = m / 3;
            float z = (th_raw[((b * 9 + m) << 14) + p] - muT[g]) * isT[g] * g_th[m] + be_th[m];
            float f = fast_tanh((off_raw[((b * 9 + m) << 14) + p] - muO[g]) * isO[g] * g_off[m] + be_off[m]);
            float r = rsqrtf(1.f + z * z);
            float fs = (float)s;
            float yy = (float)h + fs + fs * z + f * r;
            float xx = (float)w + fs + fs - z * r * f;
            yy = fminf(fmaxf(yy, 0.f), 127.f);
            xx = fminf(fmaxf(xx, 0.f), 127.f);
            int y0 = min((int)yy, 126);
            int x0 = min((int)xx, 126);
            float wy = yy - (float)y0;
            float wx = xx - (float)x0;
            const float* base = xb + (y0 << 7) + x0;
#pragma unroll
            for (int ci = 0; ci < 16; ++ci) {
                const float* qp = base + (ci << 14);
                float2 r0 = *(const float2*)qp;
                float2 r1 = *(const float2*)(qp + 128);
                float lo = fmaf(wx, r0.y - r0.x, r0.x);
                float hi = fmaf(wx, r1.y - r1.x, r1.x);
                v[ci] = fmaf(wy, hi - lo, lo);
            }
        }

        union { v8s s8; __bf16 hh[8]; } u0, u1;
#pragma unroll
        for (int ci = 0; ci < 8; ++ci) { u0.hh[ci] = (__bf16)v[ci]; u1.hh[ci] = (__bf16)v[ci + 8]; }
        *(v8s*)&smem[(lane << 6) + ((((wv << 1) + 0) + lane) & 7) * 8] = u0.s8;
        *(v8s*)&smem[(lane << 6) + ((((wv << 1) + 1) + lane) & 7) * 8] = u1.s8;
        __syncthreads();

        const short* wpk = w_pack + (((k << 2) + wv) << 10) + (lane << 3);
        v8s a0 = *(const v8s*)wpk;
        v8s a1 = *(const v8s*)(wpk + 512);

#pragma unroll
        for (int n = 0; n < 4; ++n) {
            int r = (n << 4) + i15;
            v8s b0 = *(const v8s*)&smem[(r << 6) + (((lg    ) + r) & 7) * 8];
            v8s b1 = *(const v8s*)&smem[(r << 6) + (((lg + 4) + r) & 7) * 8];
            acc[n] = __builtin_amdgcn_mfma_f32_16x16x32_bf16(a0, b0, acc[n], 0, 0, 0);
            acc[n] = __builtin_amdgcn_mfma_f32_16x16x32_bf16(a1, b1, acc[n], 0, 0, 0);
        }
        __syncthreads();
    }

#pragma unroll
    for (int r = 0; r < 4; ++r) {
        int o = (wv << 4) + (lg << 2) + r;
        float bias = b_strip[o];
        float* op = out + ((size_t)((b << 6) + o) << 14) + pix0 + i15;
#pragma unroll
        for (int n = 0; n < 4; ++n)
            op[n << 4] = acc[n][r] + bias;
    }
}

// ---------------------------------------------------------------------------
// Kernel 2b: output GN stats per (b,o). grid 256. (fallback path only)
// ---------------------------------------------------------------------------
__global__ __launch_bounds__(256) void k_stats_out(
    const float* __restrict__ out, float* __restrict__ out_stats)
{
    const int bo = blockIdx.x;
    const float4* src = (const float4*)(out + ((size_t)bo << 14));
    float s1 = 0.f, s2 = 0.f;
    for (int i = threadIdx.x; i < 4096; i += 256) {
        float4 v = src[i];
        s1 += v.x + v.y + v.z + v.w;
        s2 += v.x * v.x + v.y * v.y + v.z * v.z + v.w * v.w;
    }
#pragma unroll
    for (int d = 32; d; d >>= 1) { s1 += __shfl_down(s1, d, 64); s2 += __shfl_down(s2, d, 64); }

    __shared__ float ls1[4], ls2[4];
    const int wv = threadIdx.x >> 6;
    if ((threadIdx.x & 63) == 0) { ls1[wv] = s1; ls2[wv] = s2; }
    __syncthreads();
    if (threadIdx.x == 0) {
        out_stats[bo]       = ls1[0] + ls1[1] + ls1[2] + ls1[3];
        out_stats[256 + bo] = ls2[0] + ls2[1] + ls2[2] + ls2[3];
    }
}

// ---------------------------------------------------------------------------
// Kernel 3: output GroupNorm (16 groups of 4 channels) + ReLU, in place.
// ---------------------------------------------------------------------------
__global__ __launch_bounds__(256) void k_gn_out(
    float* __restrict__ out, const float* __restrict__ out_stats,
    const float* __restrict__ gg, const float* __restrict__ gb)
{
    const float inv_cnt = 1.f / (4.f * 16384.f);
    const int n4 = 1 << 20;
    for (int idx = blockIdx.x * 256 + threadIdx.x; idx < n4; idx += gridDim.x * 256) {
        int flat = idx << 2;
        int ch = (flat >> 14) & 63;
        int b  = flat >> 20;
        int cb = (b << 6) + ((ch >> 2) << 2);
        float s = out_stats[cb] + out_stats[cb + 1] + out_stats[cb + 2] + out_stats[cb + 3];
        float q = out_stats[256 + cb] + out_stats[256 + cb + 1] + out_stats[256 + cb + 2] + out_stats[256 + cb + 3];
        float mu   = s * inv_cnt;
        float istd = rsqrtf(fmaxf(q * inv_cnt - mu * mu, 0.f) + 1e-5f);
        float ga = gg[ch] * istd;
        float be = gb[ch] - mu * ga;
        float4 v = *reinterpret_cast<float4*>(out + flat);
        v.x = fmaxf(fmaf(v.x, ga, be), 0.f);
        v.y = fmaxf(fmaf(v.y, ga, be), 0.f);
        v.z = fmaxf(fmaf(v.z, ga, be), 0.f);
        v.w = fmaxf(fmaf(v.w, ga, be), 0.f);
        *reinterpret_cast<float4*>(out + flat) = v;
    }
}

// ---------------------------------------------------------------------------
extern "C" void kernel_launch(void* const* d_in, const int* in_sizes, int n_in,
                              void* d_out, int out_size, void* d_ws, size_t ws_size,
                              hipStream_t stream)
{
    const float* x       = (const float*)d_in[0];
    const float* w_off   = (const float*)d_in[1];
    const float* b_off   = (const float*)d_in[2];
    const float* w_th    = (const float*)d_in[3];
    const float* b_th    = (const float*)d_in[4];
    const float* g_off   = (const float*)d_in[5];
    const float* be_off  = (const float*)d_in[6];
    const float* g_th    = (const float*)d_in[7];
    const float* be_th   = (const float*)d_in[8];
    const float* w_strip = (const float*)d_in[9];
    const float* b_strip = (const float*)d_in[10];
    const float* gg      = (const float*)d_in[11];
    const float* gb      = (const float*)d_in[12];

    float* out       = (float*)d_out;
    float* ws        = (float*)d_ws;
    float* off_raw   = ws;                      // 589824 floats
    float* th_raw    = ws + 589824;             // 589824 floats
    float* stats     = ws + 1179648;            // 144 floats
    float* out_stats = ws + 1179792;            // 512 floats
    short* w_pack    = (short*)(ws + 1180304);  // 36864 shorts = 18432 floats
    short* xt        = (short*)(ws + 1198736);  // 4194304 shorts = 2097152 floats

    const size_t need_full = (size_t)(1198736 + 2097152) * sizeof(float);
    const bool big = ws_size >= need_full;

    if (big) {
        k_tr<<<1024, 256, 0, stream>>>(x, xt, w_strip, w_pack, (float4*)ws);
    } else {
        hipMemsetAsync(ws, 0, (size_t)1180304 * sizeof(float), stream);
        k_pack<<<144, 256, 0, stream>>>(w_strip, w_pack);
    }
    dim3 g1(4, 16, 32);
    k_conv<<<g1, 256, 0, stream>>>(x, w_off, b_off, w_th, b_th, off_raw, th_raw);
    k_stats<<<72, 256, 0, stream>>>(off_raw, th_raw, stats);
    if (big) {
        k_sample_strip3<<<2048, 256, 0, stream>>>(xt, off_raw, th_raw, stats,
                                                  g_off, be_off, g_th, be_th,
                                                  w_pack, b_strip, out, out_stats);
    } else {
        k_sample_strip_old<<<1024, 256, 0, stream>>>(x, off_raw, th_raw, stats,
                                                     g_off, be_off, g_th, be_th,
                                                     w_pack, b_strip, out);
        k_stats_out<<<256, 256, 0, stream>>>(out, out_stats);
    }
    k_gn_out<<<4096, 256, 0, stream>>>(out, out_stats, gg, gb);
}